// Round 13
// baseline (627.587 us; speedup 1.0000x reference)
//
#include <hip/hip_runtime.h>
#include <math.h>

#define CDIV(a,b) (((a)+(b)-1)/(b))

typedef __attribute__((ext_vector_type(8))) short bfrag;
typedef __attribute__((ext_vector_type(4))) float ffrag;

__device__ inline unsigned short f2bf(float f) {
    unsigned int u = __float_as_uint(f);
    return (unsigned short)((u + 0x7fffu + ((u >> 16) & 1u)) >> 16);
}
__device__ inline float bf2f(unsigned short u) {
    return __uint_as_float(((unsigned int)u) << 16);
}
__device__ inline float sigf(float x) {
    return __builtin_amdgcn_rcpf(1.f + __expf(-x));
}
__device__ inline float tanhfast(float x) {
    float t = __expf(-2.f * fabsf(x));
    float r = (1.f - t) * __builtin_amdgcn_rcpf(1.f + t);
    return copysignf(r, x);
}
// swizzled element offset into a [R][128] bf16 LDS tile (16B-chunk XOR swizzle)
__device__ inline int hoff(int row, int k) {
    int sw = ((k >> 3) ^ row) & 15;
    return row * 128 + sw * 8 + (k & 7);
}

// ---------------------------------------------------------------- utils
__global__ void zero_i32(int* __restrict__ p, int n) {
    int i = blockIdx.x * 256 + threadIdx.x;
    if (i < n) p[i] = 0;
}
__global__ void init_score_k(float* __restrict__ sc, const float* __restrict__ b, int n) {
    int i = blockIdx.x * 256 + threadIdx.x;
    if (i < n) sc[i] = b[0];
}

// fused prep: LSTM W pack + bsum, dense-W pack, x->bf16 convert
__global__ void prep_k(const float* __restrict__ Wih, const float* __restrict__ Whh,
                       const float* __restrict__ bih, const float* __restrict__ bhh,
                       unsigned short* __restrict__ Wp, float* __restrict__ bsum,
                       const float* __restrict__ W1, const float* __restrict__ Ws,
                       const float* __restrict__ l1w, const float* __restrict__ l2w,
                       unsigned short* __restrict__ wb,
                       const float* __restrict__ x, unsigned short* __restrict__ xb, int nx) {
    int i = blockIdx.x * 256 + threadIdx.x;
    if (i < 1024) bsum[i] = bih[i] + bhh[i];
    if (i < 262144) {
        int k = i & 255, j = (i >> 8) & 511, d = i >> 17;
        float v = (k < 128) ? Wih[((size_t)d * 512 + j) * 128 + k]
                            : Whh[((size_t)d * 512 + j) * 128 + (k - 128)];
        Wp[i] = f2bf(v);
        return;
    }
    int i2 = i - 262144;
    if (i2 < 69632) {
        float v;
        if (i2 < 16384)      v = W1[i2];
        else if (i2 < 49152) v = Ws[i2 - 16384];
        else if (i2 < 57344) v = l1w[i2 - 49152];
        else                 v = l2w[i2 - 57344];
        wb[i2] = f2bf(v);
        return;
    }
    int i3 = i2 - 69632;
    if (i3 < nx) xb[i3] = f2bf(x[i3]);
}

// ---------------------------------------------------------------- CSR build
__global__ void hist_k(const int* __restrict__ ei, int E, int ET, int* __restrict__ deg) {
    int e = blockIdx.x * 256 + threadIdx.x;
    if (e >= ET) return;
    int d = (e < E) ? ei[E + e] : e - E;
    atomicAdd(deg + d, 1);
}

__global__ __launch_bounds__(256)
void scan1_k(const int* __restrict__ deg, int* __restrict__ row_ptr,
             int* __restrict__ part, int Nn) {
    __shared__ int ls[256];
    int t = threadIdx.x;
    int base = blockIdx.x * 1024 + t * 4;
    int v[4];
    #pragma unroll
    for (int j = 0; j < 4; ++j) v[j] = (base + j < Nn) ? deg[base + j] : 0;
    int s = v[0] + v[1] + v[2] + v[3];
    ls[t] = s;
    __syncthreads();
    for (int off = 1; off < 256; off <<= 1) {
        int o = (t >= off) ? ls[t - off] : 0;
        __syncthreads();
        ls[t] += o;
        __syncthreads();
    }
    int run = ls[t] - s;
    if (t == 255) part[blockIdx.x] = ls[255];
    #pragma unroll
    for (int j = 0; j < 4; ++j) {
        if (base + j < Nn) row_ptr[base + j] = run;
        run += v[j];
    }
}
__global__ void scan2_k(int* __restrict__ part, int nb) {
    int lane = threadIdx.x;
    int v = (lane < nb) ? part[lane] : 0;
    int orig = v;
    for (int off = 1; off < 64; off <<= 1) {
        int o = __shfl_up(v, off);
        if (lane >= off) v += o;
    }
    if (lane < nb) part[lane] = v - orig;
}
__global__ void scan3_k(const int* __restrict__ part, int* __restrict__ row_ptr,
                        int* __restrict__ cursor, int Nn) {
    int i = blockIdx.x * 256 + threadIdx.x;
    if (i >= Nn) return;
    int v = row_ptr[i] + part[i >> 10];
    row_ptr[i] = v;
    cursor[i] = v;
}

__global__ void fill_k(const int* __restrict__ ei, int E, int ET,
                       int* __restrict__ cursor, int* __restrict__ csr_src) {
    int e = blockIdx.x * 256 + threadIdx.x;
    if (e >= ET) return;
    int s, d;
    if (e < E) { s = ei[e]; d = ei[E + e]; } else { s = e - E; d = s; }
    int pos = atomicAdd(cursor + d, 1);
    csr_src[pos] = s;
}

// ---------------------------------------------------------------- MFMA GEMM
template<int NT, int K, int K1, bool RELU, bool FUSE, bool BFOUT>
__global__ __launch_bounds__(256)
void gemm_mfma_k(const unsigned short* __restrict__ A1, const unsigned short* __restrict__ A2,
                 int ldA2, const unsigned short* __restrict__ Wb, const float* __restrict__ bias,
                 unsigned short* __restrict__ Cb, float* __restrict__ Cf,
                 const float* __restrict__ asl, const float* __restrict__ adl,
                 float* __restrict__ es, float* __restrict__ ed, int M)
{
    int tid = threadIdx.x;
    int wv = tid >> 6, lane = tid & 63;
    int col = lane & 15, kg = lane >> 4;
    int row0 = blockIdx.x * 64 + wv * 16;
    int mrow = row0 + col;
    bool mok = mrow < M;

    ffrag acc[NT];
    #pragma unroll
    for (int t = 0; t < NT; ++t) acc[t] = (ffrag){0.f, 0.f, 0.f, 0.f};

    #pragma unroll
    for (int ks = 0; ks < K / 32; ++ks) {
        int kk = ks * 32 + kg * 8;
        bfrag a = (bfrag){0,0,0,0,0,0,0,0};
        if (mok) {
            if (kk < K1) a = *(const bfrag*)(A1 + (size_t)mrow * K1 + kk);
            else         a = *(const bfrag*)(A2 + (size_t)mrow * ldA2 + (kk - K1));
        }
        #pragma unroll
        for (int t = 0; t < NT; ++t) {
            bfrag b = *(const bfrag*)(Wb + (size_t)(t * 16 + col) * K + kk);
            acc[t] = __builtin_amdgcn_mfma_f32_16x16x32_bf16(a, b, acc[t], 0, 0, 0);
        }
    }

    #pragma unroll
    for (int r = 0; r < 4; ++r) {
        int n = row0 + kg * 4 + r;
        bool ok = n < M;
        float e0 = 0.f, e1 = 0.f, d0 = 0.f, d1 = 0.f;
        #pragma unroll
        for (int t = 0; t < NT; ++t) {
            float v = acc[t][r];
            if (FUSE) {
                int ch = t * 16 + col;
                if (t < NT / 2) { e0 = fmaf(v, asl[ch], e0); d0 = fmaf(v, adl[ch], d0); }
                else            { e1 = fmaf(v, asl[ch], e1); d1 = fmaf(v, adl[ch], d1); }
            }
            if (bias) v += bias[t * 16 + col];
            if (RELU) v = fmaxf(v, 0.f);
            if (ok) {
                if (BFOUT) Cb[(size_t)n * (NT * 16) + t * 16 + col] = f2bf(v);
                else       Cf[(size_t)n * (NT * 16) + t * 16 + col] = v;
            }
        }
        if (FUSE) {
            #pragma unroll
            for (int mk = 1; mk < 16; mk <<= 1) {
                e0 += __shfl_xor(e0, mk); e1 += __shfl_xor(e1, mk);
                d0 += __shfl_xor(d0, mk); d1 += __shfl_xor(d1, mk);
            }
            if (col == 0 && ok) {
                es[n * 2] = e0; es[n * 2 + 1] = e1;
                ed[n * 2] = d0; ed[n * 2 + 1] = d1;
            }
        }
    }
}

// ---------------------------------------------------------------- GAT aggregate
__global__ __launch_bounds__(256)
void gat_agg_k(const int* __restrict__ csr_src, const int* __restrict__ row_ptr,
               const int* __restrict__ deg,
               const unsigned short* __restrict__ xpb, const float* __restrict__ es,
               const float* __restrict__ ed, const float* __restrict__ bias,
               unsigned short* __restrict__ out, int Nn, int relu)
{
    int wid = (blockIdx.x * 256 + threadIdx.x) >> 6;
    int lane = threadIdx.x & 63;
    if (wid >= Nn) return;
    int n = wid;
    int beg = row_ptr[n];
    int dn = deg[n];
    float2 edv = *(const float2*)(ed + n * 2);

    int   src_c = 0;
    float z0_c = 0.f, z1_c = 0.f;
    float m0 = -3e38f, m1 = -3e38f, s0 = 0.f, s1 = 0.f;
    for (int i = lane; i < dn; i += 64) {
        int s = csr_src[beg + i];
        float2 e2 = *(const float2*)(es + s * 2);
        float z0 = e2.x + edv.x; z0 = z0 > 0.f ? z0 : 0.2f * z0;
        float z1 = e2.y + edv.y; z1 = z1 > 0.f ? z1 : 0.2f * z1;
        if (i == lane) { src_c = s; z0_c = z0; z1_c = z1; }
        float nm0 = fmaxf(m0, z0);
        s0 = s0 * __expf(m0 - nm0) + __expf(z0 - nm0); m0 = nm0;
        float nm1 = fmaxf(m1, z1);
        s1 = s1 * __expf(m1 - nm1) + __expf(z1 - nm1); m1 = nm1;
    }
    #pragma unroll
    for (int off = 32; off; off >>= 1) {
        float om0 = __shfl_xor(m0, off), os0 = __shfl_xor(s0, off);
        float nm0 = fmaxf(m0, om0);
        s0 = s0 * __expf(m0 - nm0) + os0 * __expf(om0 - nm0); m0 = nm0;
        float om1 = __shfl_xor(m1, off), os1 = __shfl_xor(s1, off);
        float nm1 = fmaxf(m1, om1);
        s1 = s1 * __expf(m1 - nm1) + os1 * __expf(om1 - nm1); m1 = nm1;
    }
    float inv0 = 1.f / s0, inv1 = 1.f / s1;

    float acc0 = 0.f, acc1 = 0.f;
    if (dn <= 64) {
        // alpha-cache: convert cached logits to final attention weights ONCE
        // (moves 2 transcendentals/edge out of the gather loop — trans pipe is 1/4 rate)
        float a0_c = __expf(z0_c - m0) * inv0;
        float a1_c = __expf(z1_c - m1) * inv1;
        #pragma unroll 8
        for (int i = 0; i < dn; ++i) {
            int s = __shfl(src_c, i);
            float a0 = __shfl(a0_c, i);
            float a1 = __shfl(a1_c, i);
            float aw = (lane < 32) ? a0 : a1;
            unsigned int u = *(const unsigned int*)(xpb + (size_t)s * 128 + 2 * lane);
            acc0 = fmaf(bf2f((unsigned short)(u & 0xffff)), aw, acc0);
            acc1 = fmaf(bf2f((unsigned short)(u >> 16)), aw, acc1);
        }
    } else {
        for (int i = 0; i < dn; ++i) {
            int s = csr_src[beg + i];
            float2 e2 = *(const float2*)(es + s * 2);
            float z0 = e2.x + edv.x; z0 = z0 > 0.f ? z0 : 0.2f * z0;
            float z1 = e2.y + edv.y; z1 = z1 > 0.f ? z1 : 0.2f * z1;
            float a0 = __expf(z0 - m0) * inv0;
            float a1 = __expf(z1 - m1) * inv1;
            float aw = (lane < 32) ? a0 : a1;
            unsigned int u = *(const unsigned int*)(xpb + (size_t)s * 128 + 2 * lane);
            acc0 = fmaf(bf2f((unsigned short)(u & 0xffff)), aw, acc0);
            acc1 = fmaf(bf2f((unsigned short)(u >> 16)), aw, acc1);
        }
    }
    float2 bb = *(const float2*)(bias + 2 * lane);
    float v0 = acc0 + bb.x;
    float v1 = acc1 + bb.y;
    if (relu) { v0 = fmaxf(v0, 0.f); v1 = fmaxf(v1, 0.f); }
    unsigned int o = (unsigned int)f2bf(v0) | ((unsigned int)f2bf(v1) << 16);
    *(unsigned int*)(out + (size_t)n * 128 + 2 * lane) = o;
}

// ---------------------------------------------------------------- fused biLSTM, W-stationary, PERSISTENT blocks
// grid (256, 2): blockIdx.y = dir, 512 blocks total = 2/CU (r12 post-mortem:
// VGPR 124 < 128 allows 4 waves/SIMD, so TWO 8-wave blocks fit per CU — r12's
// 1-block grid left half the latency-hiding on the table). Each block keeps W
// in 128 stationary VGPRs (r9-proven, no spill) and loops over ~6 node-tiles.
// NO __launch_bounds__ min-occupancy arg (r6/r7 spill lesson).
__global__ __launch_bounds__(512)
void lstm_all_k(const unsigned short* __restrict__ X0, const unsigned short* __restrict__ X1,
                const unsigned short* __restrict__ X2,
                const unsigned short* __restrict__ WpB, const float* __restrict__ bsumB,
                const float* __restrict__ jkw, float* __restrict__ score, int Nn, int ntiles)
{
    __shared__ unsigned short h_lds[2][32 * 128];   // 16 KB double-buffered
    int dir = blockIdx.y;
    const unsigned short* Xs0 = dir ? X2 : X0;
    const unsigned short* Xs2 = dir ? X0 : X2;
    const unsigned short* Wp = WpB + (size_t)dir * 512 * 256;
    const float* bsum = bsumB + dir * 512;
    const float* wsc = jkw + dir * 128;

    int tid = threadIdx.x;
    int wv = tid >> 6, lane = tid & 63;
    int col = lane & 15, kg = lane >> 4;
    int t0 = dir ? 2 : 0;
    int kch = 16 * wv + col;
    float bi = bsum[kch], bf_ = bsum[128 + kch];
    float bg = bsum[256 + kch], bo = bsum[384 + kch];
    float wk = wsc[kch];

    // stationary W: 4 gate tiles x 8 K-steps, loaded once per block,
    // reused across 3 steps x ~6 node-tiles
    bfrag wreg[4][8];
    #pragma unroll
    for (int g = 0; g < 4; ++g) {
        const unsigned short* wrow = Wp + (size_t)(16 * (8 * g + wv) + col) * 256;
        #pragma unroll
        for (int ks = 0; ks < 8; ++ks)
            wreg[g][ks] = *(const bfrag*)(wrow + ks * 32 + kg * 8);
    }

    for (int tile = blockIdx.x; tile < ntiles; tile += gridDim.x) {
        int node0 = tile * 32;
        float c[2][4] = {};

        #pragma unroll
        for (int i = 0; i < 3; ++i) {
            int t = (i == 0) ? t0 : ((i == 1) ? 1 : (2 - t0));
            const unsigned short* Xt = (i == 0) ? Xs0 : ((i == 1) ? X1 : Xs2);
            const unsigned short* h_rd = h_lds[(i + 1) & 1];
            unsigned short* h_wr = h_lds[i & 1];

            ffrag acc[2][4];
            #pragma unroll
            for (int nt = 0; nt < 2; ++nt)
                #pragma unroll
                for (int g = 0; g < 4; ++g) acc[nt][g] = (ffrag){0.f, 0.f, 0.f, 0.f};

            // X half (K 0..127)
            #pragma unroll
            for (int ks = 0; ks < 4; ++ks) {
                int kk = ks * 32 + kg * 8;
                bfrag a0 = *(const bfrag*)(Xt + (size_t)(node0 + col) * 128 + kk);
                bfrag a1 = *(const bfrag*)(Xt + (size_t)(node0 + 16 + col) * 128 + kk);
                #pragma unroll
                for (int g = 0; g < 4; ++g) {
                    acc[0][g] = __builtin_amdgcn_mfma_f32_16x16x32_bf16(a0, wreg[g][ks], acc[0][g], 0, 0, 0);
                    acc[1][g] = __builtin_amdgcn_mfma_f32_16x16x32_bf16(a1, wreg[g][ks], acc[1][g], 0, 0, 0);
                }
            }

            // h half (K 128..255), skipped on first step (h==0)
            if (i > 0) {
                #pragma unroll
                for (int ks = 4; ks < 8; ++ks) {
                    int kh = (ks - 4) * 32 + kg * 8;
                    bfrag ah0 = *(const bfrag*)&h_rd[hoff(col, kh)];
                    bfrag ah1 = *(const bfrag*)&h_rd[hoff(16 + col, kh)];
                    #pragma unroll
                    for (int g = 0; g < 4; ++g) {
                        acc[0][g] = __builtin_amdgcn_mfma_f32_16x16x32_bf16(ah0, wreg[g][ks], acc[0][g], 0, 0, 0);
                        acc[1][g] = __builtin_amdgcn_mfma_f32_16x16x32_bf16(ah1, wreg[g][ks], acc[1][g], 0, 0, 0);
                    }
                }
            }

            // gates -> c/h update -> LDS h write + score contribution
            #pragma unroll
            for (int nt = 0; nt < 2; ++nt) {
                #pragma unroll
                for (int r = 0; r < 4; ++r) {
                    float gi = acc[nt][0][r] + bi;
                    float gf = acc[nt][1][r] + bf_;
                    float gg = acc[nt][2][r] + bg;
                    float go = acc[nt][3][r] + bo;
                    float si = sigf(gi);
                    float sf = sigf(gf);
                    float so = sigf(go);
                    float tg = tanhfast(gg);
                    float cn = sf * c[nt][r] + si * tg;
                    float hn = so * tanhfast(cn);
                    c[nt][r] = cn;
                    int nl = nt * 16 + kg * 4 + r;          // local node 0..31
                    h_wr[hoff(nl, kch)] = f2bf(hn);
                    float v = hn * wk;
                    #pragma unroll
                    for (int mk = 1; mk < 16; mk <<= 1) v += __shfl_xor(v, mk);
                    if (col == 0) {
                        int n = node0 + nl;
                        if (n < Nn) atomicAdd(&score[(size_t)t * Nn + n], v);
                    }
                }
            }
            __syncthreads();   // h_wr complete before next step (or next tile)
        }
    }
}

// ---------------------------------------------------------------- JK combine + head
__global__ void jk_combine_k(const float* __restrict__ score, const unsigned short* __restrict__ x0,
                             const unsigned short* __restrict__ x1, const unsigned short* __restrict__ x2,
                             unsigned short* __restrict__ jkb, int N_) {
    int gid = blockIdx.x * 256 + threadIdx.x;
    int n = gid >> 5;
    if (n >= N_) return;
    int c = (gid & 31) * 4;
    float s0 = score[n], s1 = score[N_ + n], s2 = score[2*N_ + n];
    float mx = fmaxf(s0, fmaxf(s1, s2));
    float e0 = __expf(s0 - mx), e1 = __expf(s1 - mx), e2 = __expf(s2 - mx);
    float inv = 1.f / (e0 + e1 + e2);
    float a0 = e0 * inv, a1 = e1 * inv, a2 = e2 * inv;
    size_t off = (size_t)n * 128 + c;
    ushort4 u0 = *(const ushort4*)(x0 + off);
    ushort4 u1 = *(const ushort4*)(x1 + off);
    ushort4 u2 = *(const ushort4*)(x2 + off);
    ushort4 o;
    o.x = f2bf(a0*bf2f(u0.x) + a1*bf2f(u1.x) + a2*bf2f(u2.x));
    o.y = f2bf(a0*bf2f(u0.y) + a1*bf2f(u1.y) + a2*bf2f(u2.y));
    o.z = f2bf(a0*bf2f(u0.z) + a1*bf2f(u1.z) + a2*bf2f(u2.z));
    o.w = f2bf(a0*bf2f(u0.w) + a1*bf2f(u1.w) + a2*bf2f(u2.w));
    *(ushort4*)(jkb + off) = o;
}

__global__ void final_out_k(const float* __restrict__ h2, const float* __restrict__ ow,
                            const float* __restrict__ ob, float* __restrict__ out, int N_) {
    int n = blockIdx.x * 256 + threadIdx.x;
    if (n >= N_) return;
    float l[6];
    #pragma unroll
    for (int j = 0; j < 6; ++j) l[j] = ob[j];
    for (int c = 0; c < 64; c += 4) {
        float4 h4 = *(const float4*)(h2 + (size_t)n * 64 + c);
        #pragma unroll
        for (int j = 0; j < 6; ++j) {
            l[j] += h4.x * ow[j*64 + c + 0] + h4.y * ow[j*64 + c + 1]
                  + h4.z * ow[j*64 + c + 2] + h4.w * ow[j*64 + c + 3];
        }
    }
    float mx = l[0];
    #pragma unroll
    for (int j = 1; j < 6; ++j) mx = fmaxf(mx, l[j]);
    float se = 0.f;
    #pragma unroll
    for (int j = 0; j < 6; ++j) se += __expf(l[j] - mx);
    float ls = logf(se) + mx;
    #pragma unroll
    for (int j = 0; j < 6; ++j) out[(size_t)n * 6 + j] = l[j] - ls;
}

// ---------------------------------------------------------------- launch
extern "C" void kernel_launch(void* const* d_in, const int* in_sizes, int n_in,
                              void* d_out, int out_size, void* d_ws, size_t ws_size,
                              hipStream_t stream) {
    const float* x   = (const float*)d_in[0];
    const int*   ei  = (const int*)d_in[1];
    const float* W1  = (const float*)d_in[2];
    const float* a1s = (const float*)d_in[3];
    const float* a1d = (const float*)d_in[4];
    const float* b1  = (const float*)d_in[5];
    const float* Ws  = (const float*)d_in[6];
    const float* ass = (const float*)d_in[7];
    const float* asd = (const float*)d_in[8];
    const float* bs  = (const float*)d_in[9];
    const float* Wih = (const float*)d_in[10];
    const float* Whh = (const float*)d_in[11];
    const float* bih = (const float*)d_in[12];
    const float* bhh = (const float*)d_in[13];
    const float* jkw = (const float*)d_in[14];
    const float* jkb_b = (const float*)d_in[15];
    const float* l1w = (const float*)d_in[16];
    const float* l1b = (const float*)d_in[17];
    const float* l2w = (const float*)d_in[18];
    const float* l2b = (const float*)d_in[19];
    const float* ow  = (const float*)d_in[20];
    const float* ob  = (const float*)d_in[21];
    float* out = (float*)d_out;

    int Nn = in_sizes[0] / 128;
    int E  = in_sizes[1] / 2;
    int ET = E + Nn;
    size_t Np = ((size_t)Nn + 63) & ~(size_t)63;
    size_t Fp = Np * 128;

    float* w = (float*)d_ws;
    float* es    = w;                    // [2Nn]
    float* ed    = es + 2*Nn;            // [2Nn]
    float* score = ed + 2*Nn;            // [3Nn]
    float* bsum  = score + 3*Nn;         // [1024]
    float* h2    = bsum + 1024;          // [Nn*64]
    unsigned short* xb   = (unsigned short*)(h2 + (size_t)Nn*64);  // [Fp]
    unsigned short* xpb  = xb + Fp;      // [Fp]; reused as jkb
    unsigned short* xsb0 = xpb + Fp;
    unsigned short* xsb1 = xsb0 + Fp;
    unsigned short* xsb2 = xsb1 + Fp;
    unsigned short* h1b  = xsb2 + Fp;    // [Fp] (only Nn*64 used)
    unsigned short* Wp   = h1b + Fp;     // [2*512*256]
    unsigned short* wb   = Wp + 2*512*256; // [69632]
    int* deg     = (int*)(wb + 69632);
    int* row_ptr = deg + Nn;
    int* cursor  = row_ptr + Nn;
    int* part    = cursor + Nn;          // [64]
    int* csr_src = part + 64;            // [ET]
    unsigned short* jkb = xpb;

    // ---- CSR by destination (edges identical for all 3 layers)
    int nb1 = CDIV(Nn, 1024);
    zero_i32<<<CDIV(Nn, 256), 256, 0, stream>>>(deg, Nn);
    hist_k<<<CDIV(ET, 256), 256, 0, stream>>>(ei, E, ET, deg);
    scan1_k<<<nb1, 256, 0, stream>>>(deg, row_ptr, part, Nn);
    scan2_k<<<1, 64, 0, stream>>>(part, nb1);
    scan3_k<<<CDIV(Nn, 256), 256, 0, stream>>>(part, row_ptr, cursor, Nn);
    fill_k<<<CDIV(ET, 256), 256, 0, stream>>>(ei, E, ET, cursor, csr_src);

    // ---- fused packs / converts
    int nprep = 262144 + 69632 + Nn * 128;
    prep_k<<<CDIV(nprep, 256), 256, 0, stream>>>(Wih, Whh, bih, bhh, Wp, bsum,
                                                 W1, Ws, l1w, l2w, wb, x, xb, Nn * 128);

    unsigned short* xsb_arr[3] = {xsb0, xsb1, xsb2};
    int gblk = CDIV(Nn, 64);

    for (int l = 0; l < 3; ++l) {
        const float* asl = (l == 0) ? a1s : ass + (size_t)(l-1) * 128;
        const float* adl = (l == 0) ? a1d : asd + (size_t)(l-1) * 128;
        const float* bl  = (l == 0) ? b1  : bs  + (size_t)(l-1) * 128;
        const unsigned short* Ain = (l == 0) ? xb : xsb_arr[l-1];
        const unsigned short* Wbl = wb + (size_t)l * 16384;
        gemm_mfma_k<8,128,128,false,true,true><<<gblk, 256, 0, stream>>>(
            Ain, Ain, 128, Wbl, nullptr, xpb, nullptr, asl, adl, es, ed, Nn);
        gat_agg_k<<<CDIV(Nn, 4), 256, 0, stream>>>(csr_src, row_ptr, deg, xpb, es, ed, bl,
                                                   xsb_arr[l], Nn, l > 0);
    }

    init_score_k<<<CDIV(3*Nn, 256), 256, 0, stream>>>(score, jkb_b, 3*Nn);
    int ntiles = CDIV(Nn, 32);
    int gx = ntiles < 256 ? ntiles : 256;
    lstm_all_k<<<dim3(gx, 2), 512, 0, stream>>>(xsb0, xsb1, xsb2, Wp, bsum, jkw, score, Nn, ntiles);

    jk_combine_k<<<CDIV(Nn*32, 256), 256, 0, stream>>>(score, xsb0, xsb1, xsb2, jkb, Nn);
    gemm_mfma_k<4,128,128,true,false,true><<<gblk, 256, 0, stream>>>(
        jkb, jkb, 128, wb + 49152, l1b, h1b, nullptr, nullptr, nullptr, nullptr, nullptr, Nn);
    gemm_mfma_k<4,192,64,true,false,false><<<gblk, 256, 0, stream>>>(
        h1b, xb, 128, wb + 57344, l2b, nullptr, h2, nullptr, nullptr, nullptr, nullptr, Nn);
    final_out_k<<<CDIV(Nn, 256), 256, 0, stream>>>(h2, ow, ob, out, Nn);
}

// Round 14
// 605.071 us; speedup vs baseline: 1.0372x; 1.0372x over previous
//
#include <hip/hip_runtime.h>
#include <math.h>

#define CDIV(a,b) (((a)+(b)-1)/(b))

typedef __attribute__((ext_vector_type(8))) short bfrag;
typedef __attribute__((ext_vector_type(4))) float ffrag;

__device__ inline unsigned short f2bf(float f) {
    unsigned int u = __float_as_uint(f);
    return (unsigned short)((u + 0x7fffu + ((u >> 16) & 1u)) >> 16);
}
__device__ inline float bf2f(unsigned short u) {
    return __uint_as_float(((unsigned int)u) << 16);
}
__device__ inline float sigf(float x) {
    return __builtin_amdgcn_rcpf(1.f + __expf(-x));
}
__device__ inline float tanhfast(float x) {
    float t = __expf(-2.f * fabsf(x));
    float r = (1.f - t) * __builtin_amdgcn_rcpf(1.f + t);
    return copysignf(r, x);
}
// swizzled element offset into a [R][128] bf16 LDS tile (16B-chunk XOR swizzle)
__device__ inline int hoff(int row, int k) {
    int sw = ((k >> 3) ^ row) & 15;
    return row * 128 + sw * 8 + (k & 7);
}

// ---------------------------------------------------------------- utils
__global__ void zero_i32(int* __restrict__ p, int n) {
    int i = blockIdx.x * 256 + threadIdx.x;
    if (i < n) p[i] = 0;
}

// fused prep: LSTM W pack + bsum, dense-W pack, x->bf16 convert
__global__ void prep_k(const float* __restrict__ Wih, const float* __restrict__ Whh,
                       const float* __restrict__ bih, const float* __restrict__ bhh,
                       unsigned short* __restrict__ Wp, float* __restrict__ bsum,
                       const float* __restrict__ W1, const float* __restrict__ Ws,
                       const float* __restrict__ l1w, const float* __restrict__ l2w,
                       unsigned short* __restrict__ wb,
                       const float* __restrict__ x, unsigned short* __restrict__ xb, int nx) {
    int i = blockIdx.x * 256 + threadIdx.x;
    if (i < 1024) bsum[i] = bih[i] + bhh[i];
    if (i < 262144) {
        int k = i & 255, j = (i >> 8) & 511, d = i >> 17;
        float v = (k < 128) ? Wih[((size_t)d * 512 + j) * 128 + k]
                            : Whh[((size_t)d * 512 + j) * 128 + (k - 128)];
        Wp[i] = f2bf(v);
        return;
    }
    int i2 = i - 262144;
    if (i2 < 69632) {
        float v;
        if (i2 < 16384)      v = W1[i2];
        else if (i2 < 49152) v = Ws[i2 - 16384];
        else if (i2 < 57344) v = l1w[i2 - 49152];
        else                 v = l2w[i2 - 57344];
        wb[i2] = f2bf(v);
        return;
    }
    int i3 = i2 - 69632;
    if (i3 < nx) xb[i3] = f2bf(x[i3]);
}

// ---------------------------------------------------------------- CSR build
__global__ void hist_k(const int* __restrict__ ei, int E, int ET, int* __restrict__ deg) {
    int e = blockIdx.x * 256 + threadIdx.x;
    if (e >= ET) return;
    int d = (e < E) ? ei[E + e] : e - E;
    atomicAdd(deg + d, 1);
}

__global__ __launch_bounds__(256)
void scan1_k(const int* __restrict__ deg, int* __restrict__ row_ptr,
             int* __restrict__ part, int Nn) {
    __shared__ int ls[256];
    int t = threadIdx.x;
    int base = blockIdx.x * 1024 + t * 4;
    int v[4];
    #pragma unroll
    for (int j = 0; j < 4; ++j) v[j] = (base + j < Nn) ? deg[base + j] : 0;
    int s = v[0] + v[1] + v[2] + v[3];
    ls[t] = s;
    __syncthreads();
    for (int off = 1; off < 256; off <<= 1) {
        int o = (t >= off) ? ls[t - off] : 0;
        __syncthreads();
        ls[t] += o;
        __syncthreads();
    }
    int run = ls[t] - s;
    if (t == 255) part[blockIdx.x] = ls[255];
    #pragma unroll
    for (int j = 0; j < 4; ++j) {
        if (base + j < Nn) row_ptr[base + j] = run;
        run += v[j];
    }
}
__global__ void scan2_k(int* __restrict__ part, int nb) {
    int lane = threadIdx.x;
    int v = (lane < nb) ? part[lane] : 0;
    int orig = v;
    for (int off = 1; off < 64; off <<= 1) {
        int o = __shfl_up(v, off);
        if (lane >= off) v += o;
    }
    if (lane < nb) part[lane] = v - orig;
}
__global__ void scan3_k(const int* __restrict__ part, int* __restrict__ row_ptr,
                        int* __restrict__ cursor, int Nn) {
    int i = blockIdx.x * 256 + threadIdx.x;
    if (i >= Nn) return;
    int v = row_ptr[i] + part[i >> 10];
    row_ptr[i] = v;
    cursor[i] = v;
}

__global__ void fill_k(const int* __restrict__ ei, int E, int ET,
                       int* __restrict__ cursor, int* __restrict__ csr_src) {
    int e = blockIdx.x * 256 + threadIdx.x;
    if (e >= ET) return;
    int s, d;
    if (e < E) { s = ei[e]; d = ei[E + e]; } else { s = e - E; d = s; }
    int pos = atomicAdd(cursor + d, 1);
    csr_src[pos] = s;
}

// ---------------------------------------------------------------- MFMA GEMM
template<int NT, int K, int K1, bool RELU, bool FUSE, bool BFOUT>
__global__ __launch_bounds__(256)
void gemm_mfma_k(const unsigned short* __restrict__ A1, const unsigned short* __restrict__ A2,
                 int ldA2, const unsigned short* __restrict__ Wb, const float* __restrict__ bias,
                 unsigned short* __restrict__ Cb, float* __restrict__ Cf,
                 const float* __restrict__ asl, const float* __restrict__ adl,
                 float* __restrict__ es, float* __restrict__ ed, int M)
{
    int tid = threadIdx.x;
    int wv = tid >> 6, lane = tid & 63;
    int col = lane & 15, kg = lane >> 4;
    int row0 = blockIdx.x * 64 + wv * 16;
    int mrow = row0 + col;
    bool mok = mrow < M;

    ffrag acc[NT];
    #pragma unroll
    for (int t = 0; t < NT; ++t) acc[t] = (ffrag){0.f, 0.f, 0.f, 0.f};

    #pragma unroll
    for (int ks = 0; ks < K / 32; ++ks) {
        int kk = ks * 32 + kg * 8;
        bfrag a = (bfrag){0,0,0,0,0,0,0,0};
        if (mok) {
            if (kk < K1) a = *(const bfrag*)(A1 + (size_t)mrow * K1 + kk);
            else         a = *(const bfrag*)(A2 + (size_t)mrow * ldA2 + (kk - K1));
        }
        #pragma unroll
        for (int t = 0; t < NT; ++t) {
            bfrag b = *(const bfrag*)(Wb + (size_t)(t * 16 + col) * K + kk);
            acc[t] = __builtin_amdgcn_mfma_f32_16x16x32_bf16(a, b, acc[t], 0, 0, 0);
        }
    }

    #pragma unroll
    for (int r = 0; r < 4; ++r) {
        int n = row0 + kg * 4 + r;
        bool ok = n < M;
        float e0 = 0.f, e1 = 0.f, d0 = 0.f, d1 = 0.f;
        #pragma unroll
        for (int t = 0; t < NT; ++t) {
            float v = acc[t][r];
            if (FUSE) {
                int ch = t * 16 + col;
                if (t < NT / 2) { e0 = fmaf(v, asl[ch], e0); d0 = fmaf(v, adl[ch], d0); }
                else            { e1 = fmaf(v, asl[ch], e1); d1 = fmaf(v, adl[ch], d1); }
            }
            if (bias) v += bias[t * 16 + col];
            if (RELU) v = fmaxf(v, 0.f);
            if (ok) {
                if (BFOUT) Cb[(size_t)n * (NT * 16) + t * 16 + col] = f2bf(v);
                else       Cf[(size_t)n * (NT * 16) + t * 16 + col] = v;
            }
        }
        if (FUSE) {
            #pragma unroll
            for (int mk = 1; mk < 16; mk <<= 1) {
                e0 += __shfl_xor(e0, mk); e1 += __shfl_xor(e1, mk);
                d0 += __shfl_xor(d0, mk); d1 += __shfl_xor(d1, mk);
            }
            if (col == 0 && ok) {
                es[n * 2] = e0; es[n * 2 + 1] = e1;
                ed[n * 2] = d0; ed[n * 2 + 1] = d1;
            }
        }
    }
}

// ---------------------------------------------------------------- GAT aggregate
__global__ __launch_bounds__(256)
void gat_agg_k(const int* __restrict__ csr_src, const int* __restrict__ row_ptr,
               const int* __restrict__ deg,
               const unsigned short* __restrict__ xpb, const float* __restrict__ es,
               const float* __restrict__ ed, const float* __restrict__ bias,
               unsigned short* __restrict__ out, int Nn, int relu)
{
    int wid = (blockIdx.x * 256 + threadIdx.x) >> 6;
    int lane = threadIdx.x & 63;
    if (wid >= Nn) return;
    int n = wid;
    int beg = row_ptr[n];
    int dn = deg[n];
    float2 edv = *(const float2*)(ed + n * 2);

    int   src_c = 0;
    float z0_c = 0.f, z1_c = 0.f;
    float m0 = -3e38f, m1 = -3e38f, s0 = 0.f, s1 = 0.f;
    for (int i = lane; i < dn; i += 64) {
        int s = csr_src[beg + i];
        float2 e2 = *(const float2*)(es + s * 2);
        float z0 = e2.x + edv.x; z0 = z0 > 0.f ? z0 : 0.2f * z0;
        float z1 = e2.y + edv.y; z1 = z1 > 0.f ? z1 : 0.2f * z1;
        if (i == lane) { src_c = s; z0_c = z0; z1_c = z1; }
        float nm0 = fmaxf(m0, z0);
        s0 = s0 * __expf(m0 - nm0) + __expf(z0 - nm0); m0 = nm0;
        float nm1 = fmaxf(m1, z1);
        s1 = s1 * __expf(m1 - nm1) + __expf(z1 - nm1); m1 = nm1;
    }
    #pragma unroll
    for (int off = 32; off; off >>= 1) {
        float om0 = __shfl_xor(m0, off), os0 = __shfl_xor(s0, off);
        float nm0 = fmaxf(m0, om0);
        s0 = s0 * __expf(m0 - nm0) + os0 * __expf(om0 - nm0); m0 = nm0;
        float om1 = __shfl_xor(m1, off), os1 = __shfl_xor(s1, off);
        float nm1 = fmaxf(m1, om1);
        s1 = s1 * __expf(m1 - nm1) + os1 * __expf(om1 - nm1); m1 = nm1;
    }
    float inv0 = 1.f / s0, inv1 = 1.f / s1;

    float acc0 = 0.f, acc1 = 0.f;
    if (dn <= 64) {
        // alpha-cache: convert cached logits to final attention weights ONCE
        float a0_c = __expf(z0_c - m0) * inv0;
        float a1_c = __expf(z1_c - m1) * inv1;
        #pragma unroll 8
        for (int i = 0; i < dn; ++i) {
            int s = __shfl(src_c, i);
            float a0 = __shfl(a0_c, i);
            float a1 = __shfl(a1_c, i);
            float aw = (lane < 32) ? a0 : a1;
            unsigned int u = *(const unsigned int*)(xpb + (size_t)s * 128 + 2 * lane);
            acc0 = fmaf(bf2f((unsigned short)(u & 0xffff)), aw, acc0);
            acc1 = fmaf(bf2f((unsigned short)(u >> 16)), aw, acc1);
        }
    } else {
        for (int i = 0; i < dn; ++i) {
            int s = csr_src[beg + i];
            float2 e2 = *(const float2*)(es + s * 2);
            float z0 = e2.x + edv.x; z0 = z0 > 0.f ? z0 : 0.2f * z0;
            float z1 = e2.y + edv.y; z1 = z1 > 0.f ? z1 : 0.2f * z1;
            float a0 = __expf(z0 - m0) * inv0;
            float a1 = __expf(z1 - m1) * inv1;
            float aw = (lane < 32) ? a0 : a1;
            unsigned int u = *(const unsigned int*)(xpb + (size_t)s * 128 + 2 * lane);
            acc0 = fmaf(bf2f((unsigned short)(u & 0xffff)), aw, acc0);
            acc1 = fmaf(bf2f((unsigned short)(u >> 16)), aw, acc1);
        }
    }
    float2 bb = *(const float2*)(bias + 2 * lane);
    float v0 = acc0 + bb.x;
    float v1 = acc1 + bb.y;
    if (relu) { v0 = fmaxf(v0, 0.f); v1 = fmaxf(v1, 0.f); }
    unsigned int o = (unsigned int)f2bf(v0) | ((unsigned int)f2bf(v1) << 16);
    *(unsigned int*)(out + (size_t)n * 128 + 2 * lane) = o;
}

// ---------------------------------------------------------------- fused biLSTM, W-stationary, PERSISTENT blocks
// grid (128, 2): 1 block/CU — occupancy is structurally pinned (124 arch VGPR
// + 32 acc AGPR ≈ 156/wave in the unified file -> 3 waves/SIMD -> one 8-wave
// block; r13 proved a 2nd block never co-resides). Each block keeps W in 128
// stationary VGPRs (r9) and loops ~12 node-tiles (r12: amortizes the 256KB W
// prologue). NEW (r14): score accumulation via LDS sc_s + one plain store per
// tile into PER-DIR buffers — removes 768 global atomics/tile whose vmcnt(0)
// drain stalled every barrier. NO __launch_bounds__ min-occupancy arg (r6/r7).
__global__ __launch_bounds__(512)
void lstm_all_k(const unsigned short* __restrict__ X0, const unsigned short* __restrict__ X1,
                const unsigned short* __restrict__ X2,
                const unsigned short* __restrict__ WpB, const float* __restrict__ bsumB,
                const float* __restrict__ jkw, float* __restrict__ score, int Nn, int ntiles)
{
    __shared__ unsigned short h_lds[2][32 * 128];   // 16 KB double-buffered
    __shared__ float sc_s[96];                      // [step][node] partial scores
    int dir = blockIdx.y;
    const unsigned short* Xs0 = dir ? X2 : X0;
    const unsigned short* Xs2 = dir ? X0 : X2;
    const unsigned short* Wp = WpB + (size_t)dir * 512 * 256;
    const float* bsum = bsumB + dir * 512;
    const float* wsc = jkw + dir * 128;
    float* scD = score + (size_t)dir * 3 * Nn;      // per-dir buffer, no cross-dir atomics

    int tid = threadIdx.x;
    int wv = tid >> 6, lane = tid & 63;
    int col = lane & 15, kg = lane >> 4;
    int t0 = dir ? 2 : 0;
    int kch = 16 * wv + col;
    float bi = bsum[kch], bf_ = bsum[128 + kch];
    float bg = bsum[256 + kch], bo = bsum[384 + kch];
    float wk = wsc[kch];

    // stationary W: 4 gate tiles x 8 K-steps, loaded once per block
    bfrag wreg[4][8];
    #pragma unroll
    for (int g = 0; g < 4; ++g) {
        const unsigned short* wrow = Wp + (size_t)(16 * (8 * g + wv) + col) * 256;
        #pragma unroll
        for (int ks = 0; ks < 8; ++ks)
            wreg[g][ks] = *(const bfrag*)(wrow + ks * 32 + kg * 8);
    }

    for (int tile = blockIdx.x; tile < ntiles; tile += gridDim.x) {
        int node0 = tile * 32;
        float c[2][4] = {};
        if (tid < 96) sc_s[tid] = 0.f;
        __syncthreads();

        #pragma unroll
        for (int i = 0; i < 3; ++i) {
            const unsigned short* Xt = (i == 0) ? Xs0 : ((i == 1) ? X1 : Xs2);
            const unsigned short* h_rd = h_lds[(i + 1) & 1];
            unsigned short* h_wr = h_lds[i & 1];

            ffrag acc[2][4];
            #pragma unroll
            for (int nt = 0; nt < 2; ++nt)
                #pragma unroll
                for (int g = 0; g < 4; ++g) acc[nt][g] = (ffrag){0.f, 0.f, 0.f, 0.f};

            // X half (K 0..127)
            #pragma unroll
            for (int ks = 0; ks < 4; ++ks) {
                int kk = ks * 32 + kg * 8;
                bfrag a0 = *(const bfrag*)(Xt + (size_t)(node0 + col) * 128 + kk);
                bfrag a1 = *(const bfrag*)(Xt + (size_t)(node0 + 16 + col) * 128 + kk);
                #pragma unroll
                for (int g = 0; g < 4; ++g) {
                    acc[0][g] = __builtin_amdgcn_mfma_f32_16x16x32_bf16(a0, wreg[g][ks], acc[0][g], 0, 0, 0);
                    acc[1][g] = __builtin_amdgcn_mfma_f32_16x16x32_bf16(a1, wreg[g][ks], acc[1][g], 0, 0, 0);
                }
            }

            // h half (K 128..255), skipped on first step (h==0)
            if (i > 0) {
                #pragma unroll
                for (int ks = 4; ks < 8; ++ks) {
                    int kh = (ks - 4) * 32 + kg * 8;
                    bfrag ah0 = *(const bfrag*)&h_rd[hoff(col, kh)];
                    bfrag ah1 = *(const bfrag*)&h_rd[hoff(16 + col, kh)];
                    #pragma unroll
                    for (int g = 0; g < 4; ++g) {
                        acc[0][g] = __builtin_amdgcn_mfma_f32_16x16x32_bf16(ah0, wreg[g][ks], acc[0][g], 0, 0, 0);
                        acc[1][g] = __builtin_amdgcn_mfma_f32_16x16x32_bf16(ah1, wreg[g][ks], acc[1][g], 0, 0, 0);
                    }
                }
            }

            // gates -> c/h update -> LDS h write + LDS score accumulation
            #pragma unroll
            for (int nt = 0; nt < 2; ++nt) {
                #pragma unroll
                for (int r = 0; r < 4; ++r) {
                    float gi = acc[nt][0][r] + bi;
                    float gf = acc[nt][1][r] + bf_;
                    float gg = acc[nt][2][r] + bg;
                    float go = acc[nt][3][r] + bo;
                    float si = sigf(gi);
                    float sf = sigf(gf);
                    float so = sigf(go);
                    float tg = tanhfast(gg);
                    float cn = sf * c[nt][r] + si * tg;
                    float hn = so * tanhfast(cn);
                    c[nt][r] = cn;
                    int nl = nt * 16 + kg * 4 + r;          // local node 0..31
                    h_wr[hoff(nl, kch)] = f2bf(hn);
                    float v = hn * wk;
                    #pragma unroll
                    for (int mk = 1; mk < 16; mk <<= 1) v += __shfl_xor(v, mk);
                    if (col == 0) atomicAdd(&sc_s[i * 32 + nl], v);
                }
            }
            __syncthreads();   // h_wr + sc_s complete before next step
        }

        // write per-tile scores (plain stores, per-dir buffer)
        if (tid < 96) {
            int ii = tid >> 5, nl = tid & 31;
            int t = (ii == 0) ? t0 : ((ii == 1) ? 1 : (2 - t0));
            int n = node0 + nl;
            if (n < Nn) scD[(size_t)t * Nn + n] = sc_s[tid];
        }
        __syncthreads();   // sc_s reads done before next tile zeroes it
    }
}

// ---------------------------------------------------------------- JK combine + head
__global__ void jk_combine_k(const float* __restrict__ scA, const float* __restrict__ scB,
                             const float* __restrict__ jkbias,
                             const unsigned short* __restrict__ x0,
                             const unsigned short* __restrict__ x1, const unsigned short* __restrict__ x2,
                             unsigned short* __restrict__ jkb, int N_) {
    int gid = blockIdx.x * 256 + threadIdx.x;
    int n = gid >> 5;
    if (n >= N_) return;
    int c = (gid & 31) * 4;
    float b = jkbias[0];
    float s0 = b + scA[n] + scB[n];
    float s1 = b + scA[N_ + n] + scB[N_ + n];
    float s2 = b + scA[2*N_ + n] + scB[2*N_ + n];
    float mx = fmaxf(s0, fmaxf(s1, s2));
    float e0 = __expf(s0 - mx), e1 = __expf(s1 - mx), e2 = __expf(s2 - mx);
    float inv = 1.f / (e0 + e1 + e2);
    float a0 = e0 * inv, a1 = e1 * inv, a2 = e2 * inv;
    size_t off = (size_t)n * 128 + c;
    ushort4 u0 = *(const ushort4*)(x0 + off);
    ushort4 u1 = *(const ushort4*)(x1 + off);
    ushort4 u2 = *(const ushort4*)(x2 + off);
    ushort4 o;
    o.x = f2bf(a0*bf2f(u0.x) + a1*bf2f(u1.x) + a2*bf2f(u2.x));
    o.y = f2bf(a0*bf2f(u0.y) + a1*bf2f(u1.y) + a2*bf2f(u2.y));
    o.z = f2bf(a0*bf2f(u0.z) + a1*bf2f(u1.z) + a2*bf2f(u2.z));
    o.w = f2bf(a0*bf2f(u0.w) + a1*bf2f(u1.w) + a2*bf2f(u2.w));
    *(ushort4*)(jkb + off) = o;
}

__global__ void final_out_k(const float* __restrict__ h2, const float* __restrict__ ow,
                            const float* __restrict__ ob, float* __restrict__ out, int N_) {
    int n = blockIdx.x * 256 + threadIdx.x;
    if (n >= N_) return;
    float l[6];
    #pragma unroll
    for (int j = 0; j < 6; ++j) l[j] = ob[j];
    for (int c = 0; c < 64; c += 4) {
        float4 h4 = *(const float4*)(h2 + (size_t)n * 64 + c);
        #pragma unroll
        for (int j = 0; j < 6; ++j) {
            l[j] += h4.x * ow[j*64 + c + 0] + h4.y * ow[j*64 + c + 1]
                  + h4.z * ow[j*64 + c + 2] + h4.w * ow[j*64 + c + 3];
        }
    }
    float mx = l[0];
    #pragma unroll
    for (int j = 1; j < 6; ++j) mx = fmaxf(mx, l[j]);
    float se = 0.f;
    #pragma unroll
    for (int j = 0; j < 6; ++j) se += __expf(l[j] - mx);
    float ls = logf(se) + mx;
    #pragma unroll
    for (int j = 0; j < 6; ++j) out[(size_t)n * 6 + j] = l[j] - ls;
}

// ---------------------------------------------------------------- launch
extern "C" void kernel_launch(void* const* d_in, const int* in_sizes, int n_in,
                              void* d_out, int out_size, void* d_ws, size_t ws_size,
                              hipStream_t stream) {
    const float* x   = (const float*)d_in[0];
    const int*   ei  = (const int*)d_in[1];
    const float* W1  = (const float*)d_in[2];
    const float* a1s = (const float*)d_in[3];
    const float* a1d = (const float*)d_in[4];
    const float* b1  = (const float*)d_in[5];
    const float* Ws  = (const float*)d_in[6];
    const float* ass = (const float*)d_in[7];
    const float* asd = (const float*)d_in[8];
    const float* bs  = (const float*)d_in[9];
    const float* Wih = (const float*)d_in[10];
    const float* Whh = (const float*)d_in[11];
    const float* bih = (const float*)d_in[12];
    const float* bhh = (const float*)d_in[13];
    const float* jkw = (const float*)d_in[14];
    const float* jkb_b = (const float*)d_in[15];
    const float* l1w = (const float*)d_in[16];
    const float* l1b = (const float*)d_in[17];
    const float* l2w = (const float*)d_in[18];
    const float* l2b = (const float*)d_in[19];
    const float* ow  = (const float*)d_in[20];
    const float* ob  = (const float*)d_in[21];
    float* out = (float*)d_out;

    int Nn = in_sizes[0] / 128;
    int E  = in_sizes[1] / 2;
    int ET = E + Nn;
    size_t Np = ((size_t)Nn + 63) & ~(size_t)63;
    size_t Fp = Np * 128;

    float* w = (float*)d_ws;
    float* es    = w;                    // [2Nn]
    float* ed    = es + 2*Nn;            // [2Nn]
    float* score = ed + 2*Nn;            // [6Nn] (two per-dir [3Nn] buffers)
    float* bsum  = score + 6*Nn;         // [1024]
    float* h2    = bsum + 1024;          // [Nn*64]
    unsigned short* xb   = (unsigned short*)(h2 + (size_t)Nn*64);  // [Fp]
    unsigned short* xpb  = xb + Fp;      // [Fp]; reused as jkb
    unsigned short* xsb0 = xpb + Fp;
    unsigned short* xsb1 = xsb0 + Fp;
    unsigned short* xsb2 = xsb1 + Fp;
    unsigned short* h1b  = xsb2 + Fp;    // [Fp] (only Nn*64 used)
    unsigned short* Wp   = h1b + Fp;     // [2*512*256]
    unsigned short* wb   = Wp + 2*512*256; // [69632]
    int* deg     = (int*)(wb + 69632);
    int* row_ptr = deg + Nn;
    int* cursor  = row_ptr + Nn;
    int* part    = cursor + Nn;          // [64]
    int* csr_src = part + 64;            // [ET]
    unsigned short* jkb = xpb;

    // ---- CSR by destination (edges identical for all 3 layers)
    int nb1 = CDIV(Nn, 1024);
    zero_i32<<<CDIV(Nn, 256), 256, 0, stream>>>(deg, Nn);
    hist_k<<<CDIV(ET, 256), 256, 0, stream>>>(ei, E, ET, deg);
    scan1_k<<<nb1, 256, 0, stream>>>(deg, row_ptr, part, Nn);
    scan2_k<<<1, 64, 0, stream>>>(part, nb1);
    scan3_k<<<CDIV(Nn, 256), 256, 0, stream>>>(part, row_ptr, cursor, Nn);
    fill_k<<<CDIV(ET, 256), 256, 0, stream>>>(ei, E, ET, cursor, csr_src);

    // ---- fused packs / converts
    int nprep = 262144 + 69632 + Nn * 128;
    prep_k<<<CDIV(nprep, 256), 256, 0, stream>>>(Wih, Whh, bih, bhh, Wp, bsum,
                                                 W1, Ws, l1w, l2w, wb, x, xb, Nn * 128);

    unsigned short* xsb_arr[3] = {xsb0, xsb1, xsb2};
    int gblk = CDIV(Nn, 64);

    for (int l = 0; l < 3; ++l) {
        const float* asl = (l == 0) ? a1s : ass + (size_t)(l-1) * 128;
        const float* adl = (l == 0) ? a1d : asd + (size_t)(l-1) * 128;
        const float* bl  = (l == 0) ? b1  : bs  + (size_t)(l-1) * 128;
        const unsigned short* Ain = (l == 0) ? xb : xsb_arr[l-1];
        const unsigned short* Wbl = wb + (size_t)l * 16384;
        gemm_mfma_k<8,128,128,false,true,true><<<gblk, 256, 0, stream>>>(
            Ain, Ain, 128, Wbl, nullptr, xpb, nullptr, asl, adl, es, ed, Nn);
        gat_agg_k<<<CDIV(Nn, 4), 256, 0, stream>>>(csr_src, row_ptr, deg, xpb, es, ed, bl,
                                                   xsb_arr[l], Nn, l > 0);
    }

    int ntiles = CDIV(Nn, 32);
    int gx = ntiles < 128 ? ntiles : 128;
    lstm_all_k<<<dim3(gx, 2), 512, 0, stream>>>(xsb0, xsb1, xsb2, Wp, bsum, jkw, score, Nn, ntiles);

    jk_combine_k<<<CDIV(Nn*32, 256), 256, 0, stream>>>(score, score + (size_t)3*Nn, jkb_b,
                                                       xsb0, xsb1, xsb2, jkb, Nn);
    gemm_mfma_k<4,128,128,true,false,true><<<gblk, 256, 0, stream>>>(
        jkb, jkb, 128, wb + 49152, l1b, h1b, nullptr, nullptr, nullptr, nullptr, nullptr, Nn);
    gemm_mfma_k<4,192,64,true,false,false><<<gblk, 256, 0, stream>>>(
        h1b, xb, 128, wb + 57344, l2b, nullptr, h2, nullptr, nullptr, nullptr, nullptr, Nn);
    final_out_k<<<CDIV(Nn, 256), 256, 0, stream>>>(h2, ow, ob, out, Nn);
}

// Round 16
// 551.355 us; speedup vs baseline: 1.1383x; 1.0974x over previous
//
#include <hip/hip_runtime.h>
#include <math.h>

#define CDIV(a,b) (((a)+(b)-1)/(b))

typedef __attribute__((ext_vector_type(8))) short bfrag;
typedef __attribute__((ext_vector_type(4))) float ffrag;

__device__ inline unsigned short f2bf(float f) {
    unsigned int u = __float_as_uint(f);
    return (unsigned short)((u + 0x7fffu + ((u >> 16) & 1u)) >> 16);
}
__device__ inline float bf2f(unsigned short u) {
    return __uint_as_float(((unsigned int)u) << 16);
}
__device__ inline float sigf(float x) {
    return __builtin_amdgcn_rcpf(1.f + __expf(-x));
}
__device__ inline float tanhfast(float x) {
    float t = __expf(-2.f * fabsf(x));
    float r = (1.f - t) * __builtin_amdgcn_rcpf(1.f + t);
    return copysignf(r, x);
}
// swizzled element offset into a [R][128] bf16 LDS tile (16B-chunk XOR swizzle)
__device__ inline int hoff(int row, int k) {
    int sw = ((k >> 3) ^ row) & 15;
    return row * 128 + sw * 8 + (k & 7);
}

// ---------------------------------------------------------------- utils
__global__ void zero_i32(int* __restrict__ p, int n) {
    int i = blockIdx.x * 256 + threadIdx.x;
    if (i < n) p[i] = 0;
}

// fused prep: LSTM W pack + bsum, dense-W pack, x->bf16 convert
__global__ void prep_k(const float* __restrict__ Wih, const float* __restrict__ Whh,
                       const float* __restrict__ bih, const float* __restrict__ bhh,
                       unsigned short* __restrict__ Wp, float* __restrict__ bsum,
                       const float* __restrict__ W1, const float* __restrict__ Ws,
                       const float* __restrict__ l1w, const float* __restrict__ l2w,
                       unsigned short* __restrict__ wb,
                       const float* __restrict__ x, unsigned short* __restrict__ xb, int nx) {
    int i = blockIdx.x * 256 + threadIdx.x;
    if (i < 1024) bsum[i] = bih[i] + bhh[i];
    if (i < 262144) {
        int k = i & 255, j = (i >> 8) & 511, d = i >> 17;
        float v = (k < 128) ? Wih[((size_t)d * 512 + j) * 128 + k]
                            : Whh[((size_t)d * 512 + j) * 128 + (k - 128)];
        Wp[i] = f2bf(v);
        return;
    }
    int i2 = i - 262144;
    if (i2 < 69632) {
        float v;
        if (i2 < 16384)      v = W1[i2];
        else if (i2 < 49152) v = Ws[i2 - 16384];
        else if (i2 < 57344) v = l1w[i2 - 49152];
        else                 v = l2w[i2 - 57344];
        wb[i2] = f2bf(v);
        return;
    }
    int i3 = i2 - 69632;
    if (i3 < nx) xb[i3] = f2bf(x[i3]);
}

// ---------------------------------------------------------------- CSR build
__global__ void hist_k(const int* __restrict__ ei, int E, int ET, int* __restrict__ deg) {
    int e = blockIdx.x * 256 + threadIdx.x;
    if (e >= ET) return;
    int d = (e < E) ? ei[E + e] : e - E;
    atomicAdd(deg + d, 1);
}

__global__ __launch_bounds__(256)
void scan1_k(const int* __restrict__ deg, int* __restrict__ row_ptr,
             int* __restrict__ part, int Nn) {
    __shared__ int ls[256];
    int t = threadIdx.x;
    int base = blockIdx.x * 1024 + t * 4;
    int v[4];
    #pragma unroll
    for (int j = 0; j < 4; ++j) v[j] = (base + j < Nn) ? deg[base + j] : 0;
    int s = v[0] + v[1] + v[2] + v[3];
    ls[t] = s;
    __syncthreads();
    for (int off = 1; off < 256; off <<= 1) {
        int o = (t >= off) ? ls[t - off] : 0;
        __syncthreads();
        ls[t] += o;
        __syncthreads();
    }
    int run = ls[t] - s;
    if (t == 255) part[blockIdx.x] = ls[255];
    #pragma unroll
    for (int j = 0; j < 4; ++j) {
        if (base + j < Nn) row_ptr[base + j] = run;
        run += v[j];
    }
}
__global__ void scan2_k(int* __restrict__ part, int nb) {
    int lane = threadIdx.x;
    int v = (lane < nb) ? part[lane] : 0;
    int orig = v;
    for (int off = 1; off < 64; off <<= 1) {
        int o = __shfl_up(v, off);
        if (lane >= off) v += o;
    }
    if (lane < nb) part[lane] = v - orig;
}
__global__ void scan3_k(const int* __restrict__ part, int* __restrict__ row_ptr,
                        int* __restrict__ cursor, int Nn) {
    int i = blockIdx.x * 256 + threadIdx.x;
    if (i >= Nn) return;
    int v = row_ptr[i] + part[i >> 10];
    row_ptr[i] = v;
    cursor[i] = v;
}

__global__ void fill_k(const int* __restrict__ ei, int E, int ET,
                       int* __restrict__ cursor, int* __restrict__ csr_src) {
    int e = blockIdx.x * 256 + threadIdx.x;
    if (e >= ET) return;
    int s, d;
    if (e < E) { s = ei[e]; d = ei[E + e]; } else { s = e - E; d = s; }
    int pos = atomicAdd(cursor + d, 1);
    csr_src[pos] = s;
}

// ---------------------------------------------------------------- MFMA GEMM
template<int NT, int K, int K1, bool RELU, bool FUSE, bool BFOUT>
__global__ __launch_bounds__(256)
void gemm_mfma_k(const unsigned short* __restrict__ A1, const unsigned short* __restrict__ A2,
                 int ldA2, const unsigned short* __restrict__ Wb, const float* __restrict__ bias,
                 unsigned short* __restrict__ Cb, float* __restrict__ Cf,
                 const float* __restrict__ asl, const float* __restrict__ adl,
                 float* __restrict__ es, float* __restrict__ ed, int M)
{
    int tid = threadIdx.x;
    int wv = tid >> 6, lane = tid & 63;
    int col = lane & 15, kg = lane >> 4;
    int row0 = blockIdx.x * 64 + wv * 16;
    int mrow = row0 + col;
    bool mok = mrow < M;

    ffrag acc[NT];
    #pragma unroll
    for (int t = 0; t < NT; ++t) acc[t] = (ffrag){0.f, 0.f, 0.f, 0.f};

    #pragma unroll
    for (int ks = 0; ks < K / 32; ++ks) {
        int kk = ks * 32 + kg * 8;
        bfrag a = (bfrag){0,0,0,0,0,0,0,0};
        if (mok) {
            if (kk < K1) a = *(const bfrag*)(A1 + (size_t)mrow * K1 + kk);
            else         a = *(const bfrag*)(A2 + (size_t)mrow * ldA2 + (kk - K1));
        }
        #pragma unroll
        for (int t = 0; t < NT; ++t) {
            bfrag b = *(const bfrag*)(Wb + (size_t)(t * 16 + col) * K + kk);
            acc[t] = __builtin_amdgcn_mfma_f32_16x16x32_bf16(a, b, acc[t], 0, 0, 0);
        }
    }

    #pragma unroll
    for (int r = 0; r < 4; ++r) {
        int n = row0 + kg * 4 + r;
        bool ok = n < M;
        float e0 = 0.f, e1 = 0.f, d0 = 0.f, d1 = 0.f;
        #pragma unroll
        for (int t = 0; t < NT; ++t) {
            float v = acc[t][r];
            if (FUSE) {
                int ch = t * 16 + col;
                if (t < NT / 2) { e0 = fmaf(v, asl[ch], e0); d0 = fmaf(v, adl[ch], d0); }
                else            { e1 = fmaf(v, asl[ch], e1); d1 = fmaf(v, adl[ch], d1); }
            }
            if (bias) v += bias[t * 16 + col];
            if (RELU) v = fmaxf(v, 0.f);
            if (ok) {
                if (BFOUT) Cb[(size_t)n * (NT * 16) + t * 16 + col] = f2bf(v);
                else       Cf[(size_t)n * (NT * 16) + t * 16 + col] = v;
            }
        }
        if (FUSE) {
            #pragma unroll
            for (int mk = 1; mk < 16; mk <<= 1) {
                e0 += __shfl_xor(e0, mk); e1 += __shfl_xor(e1, mk);
                d0 += __shfl_xor(d0, mk); d1 += __shfl_xor(d1, mk);
            }
            if (col == 0 && ok) {
                es[n * 2] = e0; es[n * 2 + 1] = e1;
                ed[n * 2] = d0; ed[n * 2 + 1] = d1;
            }
        }
    }
}

// ---------------------------------------------------------------- GAT aggregate
// 16 lanes per node (4 nodes/wave). r15 LESSON: the cached-alpha shuffles were
// inside a divergent ternary — lanes 0-7 shuffled a0_c while the source lanes
// 8-15 sat in the other branch arm (inactive source lane = undefined data) ->
// absmax 0.297. FIX: execute BOTH shuffles unconditionally (r14-proven idiom)
// and select after. Also exact 1/s instead of rcpf.
__global__ __launch_bounds__(256)
void gat_agg_k(const int* __restrict__ csr_src, const int* __restrict__ row_ptr,
               const int* __restrict__ deg,
               const unsigned short* __restrict__ xpb, const float* __restrict__ es,
               const float* __restrict__ ed, const float* __restrict__ bias,
               unsigned short* __restrict__ out, int Nn, int relu)
{
    int tid = threadIdx.x;
    int l16 = tid & 15;
    int n = blockIdx.x * 16 + (tid >> 4);
    if (n >= Nn) return;
    int beg = row_ptr[n];
    int dn = deg[n];
    float2 edv = *(const float2*)(ed + n * 2);

    // pass 1: online (max, sum) over edges, both heads; lane l16 caches edge l16
    int   src_c = 0;
    float z0_c = 0.f, z1_c = 0.f;
    float m0 = -3e38f, m1 = -3e38f, s0 = 0.f, s1 = 0.f;
    for (int i = l16; i < dn; i += 16) {
        int s = csr_src[beg + i];
        float2 e2 = *(const float2*)(es + s * 2);
        float z0 = e2.x + edv.x; z0 = z0 > 0.f ? z0 : 0.2f * z0;
        float z1 = e2.y + edv.y; z1 = z1 > 0.f ? z1 : 0.2f * z1;
        if (i == l16) { src_c = s; z0_c = z0; z1_c = z1; }
        float nm0 = fmaxf(m0, z0);
        s0 = s0 * __expf(m0 - nm0) + __expf(z0 - nm0); m0 = nm0;
        float nm1 = fmaxf(m1, z1);
        s1 = s1 * __expf(m1 - nm1) + __expf(z1 - nm1); m1 = nm1;
    }
    #pragma unroll
    for (int off = 8; off; off >>= 1) {   // butterfly within the 16-lane group
        float om0 = __shfl_xor(m0, off), os0 = __shfl_xor(s0, off);
        float nm0 = fmaxf(m0, om0);
        s0 = s0 * __expf(m0 - nm0) + os0 * __expf(om0 - nm0); m0 = nm0;
        float om1 = __shfl_xor(m1, off), os1 = __shfl_xor(s1, off);
        float nm1 = fmaxf(m1, om1);
        s1 = s1 * __expf(m1 - nm1) + os1 * __expf(om1 - nm1); m1 = nm1;
    }
    float inv0 = 1.f / s0, inv1 = 1.f / s1;

    // alpha for the cached edge (valid where l16 < min(dn,16))
    float a0_c = __expf(z0_c - m0) * inv0;
    float a1_c = __expf(z1_c - m1) * inv1;

    // pass 2: lane owns channels l16*8 .. l16*8+7 (head = l16<8 ? 0 : 1)
    int gbase = (tid & 63) & ~15;   // wave-local base lane of this group
    float acc[8] = {};
    for (int i = 0; i < dn; ++i) {
        int s; float aw;
        if (i < 16) {               // uniform branch; shuffles OUTSIDE any lane split
            int sl = gbase + i;
            int   sv = __shfl(src_c, sl);
            float A0 = __shfl(a0_c, sl);
            float A1 = __shfl(a1_c, sl);
            s = sv;
            aw = (l16 < 8) ? A0 : A1;
        } else {
            s = csr_src[beg + i];
            float2 e2 = *(const float2*)(es + s * 2);
            float z0 = e2.x + edv.x; z0 = z0 > 0.f ? z0 : 0.2f * z0;
            float z1 = e2.y + edv.y; z1 = z1 > 0.f ? z1 : 0.2f * z1;
            float aw0 = __expf(z0 - m0) * inv0;
            float aw1 = __expf(z1 - m1) * inv1;
            aw = (l16 < 8) ? aw0 : aw1;
        }
        bfrag v = *(const bfrag*)(xpb + (size_t)s * 128 + l16 * 8);
        #pragma unroll
        for (int j = 0; j < 8; ++j)
            acc[j] = fmaf(bf2f((unsigned short)v[j]), aw, acc[j]);
    }

    // epilogue: bias + relu + bf16 pack + 16B store
    float4 b0 = *(const float4*)(bias + l16 * 8);
    float4 b1 = *(const float4*)(bias + l16 * 8 + 4);
    float vb[8] = {b0.x, b0.y, b0.z, b0.w, b1.x, b1.y, b1.z, b1.w};
    unsigned int wds[4];
    #pragma unroll
    for (int j = 0; j < 4; ++j) {
        float v0 = acc[2*j]   + vb[2*j];
        float v1 = acc[2*j+1] + vb[2*j+1];
        if (relu) { v0 = fmaxf(v0, 0.f); v1 = fmaxf(v1, 0.f); }
        wds[j] = (unsigned int)f2bf(v0) | ((unsigned int)f2bf(v1) << 16);
    }
    *(uint4*)(out + (size_t)n * 128 + l16 * 8) = make_uint4(wds[0], wds[1], wds[2], wds[3]);
}

// ---------------------------------------------------------------- fused biLSTM, W-stationary, PERSISTENT blocks
// grid (128, 2): 1 block/CU — occupancy structurally pinned (124 arch VGPR +
// 32 acc AGPR ≈ 156/wave unified -> 3 waves/SIMD -> one 8-wave block). W in 128
// stationary VGPRs (r9), persistent over ~12 node-tiles (r12), LDS score
// accumulation + per-dir buffers (r14). NO min-occupancy launch_bounds (r6/r7).
__global__ __launch_bounds__(512)
void lstm_all_k(const unsigned short* __restrict__ X0, const unsigned short* __restrict__ X1,
                const unsigned short* __restrict__ X2,
                const unsigned short* __restrict__ WpB, const float* __restrict__ bsumB,
                const float* __restrict__ jkw, float* __restrict__ score, int Nn, int ntiles)
{
    __shared__ unsigned short h_lds[2][32 * 128];   // 16 KB double-buffered
    __shared__ float sc_s[96];                      // [step][node] partial scores
    int dir = blockIdx.y;
    const unsigned short* Xs0 = dir ? X2 : X0;
    const unsigned short* Xs2 = dir ? X0 : X2;
    const unsigned short* Wp = WpB + (size_t)dir * 512 * 256;
    const float* bsum = bsumB + dir * 512;
    const float* wsc = jkw + dir * 128;
    float* scD = score + (size_t)dir * 3 * Nn;      // per-dir buffer

    int tid = threadIdx.x;
    int wv = tid >> 6, lane = tid & 63;
    int col = lane & 15, kg = lane >> 4;
    int t0 = dir ? 2 : 0;
    int kch = 16 * wv + col;
    float bi = bsum[kch], bf_ = bsum[128 + kch];
    float bg = bsum[256 + kch], bo = bsum[384 + kch];
    float wk = wsc[kch];

    // stationary W: 4 gate tiles x 8 K-steps, loaded once per block
    bfrag wreg[4][8];
    #pragma unroll
    for (int g = 0; g < 4; ++g) {
        const unsigned short* wrow = Wp + (size_t)(16 * (8 * g + wv) + col) * 256;
        #pragma unroll
        for (int ks = 0; ks < 8; ++ks)
            wreg[g][ks] = *(const bfrag*)(wrow + ks * 32 + kg * 8);
    }

    for (int tile = blockIdx.x; tile < ntiles; tile += gridDim.x) {
        int node0 = tile * 32;
        float c[2][4] = {};
        if (tid < 96) sc_s[tid] = 0.f;
        __syncthreads();

        #pragma unroll
        for (int i = 0; i < 3; ++i) {
            const unsigned short* Xt = (i == 0) ? Xs0 : ((i == 1) ? X1 : Xs2);
            const unsigned short* h_rd = h_lds[(i + 1) & 1];
            unsigned short* h_wr = h_lds[i & 1];

            ffrag acc[2][4];
            #pragma unroll
            for (int nt = 0; nt < 2; ++nt)
                #pragma unroll
                for (int g = 0; g < 4; ++g) acc[nt][g] = (ffrag){0.f, 0.f, 0.f, 0.f};

            // X half (K 0..127)
            #pragma unroll
            for (int ks = 0; ks < 4; ++ks) {
                int kk = ks * 32 + kg * 8;
                bfrag a0 = *(const bfrag*)(Xt + (size_t)(node0 + col) * 128 + kk);
                bfrag a1 = *(const bfrag*)(Xt + (size_t)(node0 + 16 + col) * 128 + kk);
                #pragma unroll
                for (int g = 0; g < 4; ++g) {
                    acc[0][g] = __builtin_amdgcn_mfma_f32_16x16x32_bf16(a0, wreg[g][ks], acc[0][g], 0, 0, 0);
                    acc[1][g] = __builtin_amdgcn_mfma_f32_16x16x32_bf16(a1, wreg[g][ks], acc[1][g], 0, 0, 0);
                }
            }

            // h half (K 128..255), skipped on first step (h==0)
            if (i > 0) {
                #pragma unroll
                for (int ks = 4; ks < 8; ++ks) {
                    int kh = (ks - 4) * 32 + kg * 8;
                    bfrag ah0 = *(const bfrag*)&h_rd[hoff(col, kh)];
                    bfrag ah1 = *(const bfrag*)&h_rd[hoff(16 + col, kh)];
                    #pragma unroll
                    for (int g = 0; g < 4; ++g) {
                        acc[0][g] = __builtin_amdgcn_mfma_f32_16x16x32_bf16(ah0, wreg[g][ks], acc[0][g], 0, 0, 0);
                        acc[1][g] = __builtin_amdgcn_mfma_f32_16x16x32_bf16(ah1, wreg[g][ks], acc[1][g], 0, 0, 0);
                    }
                }
            }

            // gates -> c/h update -> LDS h write + LDS score accumulation
            #pragma unroll
            for (int nt = 0; nt < 2; ++nt) {
                #pragma unroll
                for (int r = 0; r < 4; ++r) {
                    float gi = acc[nt][0][r] + bi;
                    float gf = acc[nt][1][r] + bf_;
                    float gg = acc[nt][2][r] + bg;
                    float go = acc[nt][3][r] + bo;
                    float si = sigf(gi);
                    float sf = sigf(gf);
                    float so = sigf(go);
                    float tg = tanhfast(gg);
                    float cn = sf * c[nt][r] + si * tg;
                    float hn = so * tanhfast(cn);
                    c[nt][r] = cn;
                    int nl = nt * 16 + kg * 4 + r;          // local node 0..31
                    h_wr[hoff(nl, kch)] = f2bf(hn);
                    float v = hn * wk;
                    #pragma unroll
                    for (int mk = 1; mk < 16; mk <<= 1) v += __shfl_xor(v, mk);
                    if (col == 0) atomicAdd(&sc_s[i * 32 + nl], v);
                }
            }
            __syncthreads();   // h_wr + sc_s complete before next step
        }

        // write per-tile scores (plain stores, per-dir buffer)
        if (tid < 96) {
            int ii = tid >> 5, nl = tid & 31;
            int t = (ii == 0) ? t0 : ((ii == 1) ? 1 : (2 - t0));
            int n = node0 + nl;
            if (n < Nn) scD[(size_t)t * Nn + n] = sc_s[tid];
        }
        __syncthreads();   // sc_s reads done before next tile zeroes it
    }
}

// ---------------------------------------------------------------- JK combine + head
__global__ void jk_combine_k(const float* __restrict__ scA, const float* __restrict__ scB,
                             const float* __restrict__ jkbias,
                             const unsigned short* __restrict__ x0,
                             const unsigned short* __restrict__ x1, const unsigned short* __restrict__ x2,
                             unsigned short* __restrict__ jkb, int N_) {
    int gid = blockIdx.x * 256 + threadIdx.x;
    int n = gid >> 5;
    if (n >= N_) return;
    int c = (gid & 31) * 4;
    float b = jkbias[0];
    float s0 = b + scA[n] + scB[n];
    float s1 = b + scA[N_ + n] + scB[N_ + n];
    float s2 = b + scA[2*N_ + n] + scB[2*N_ + n];
    float mx = fmaxf(s0, fmaxf(s1, s2));
    float e0 = __expf(s0 - mx), e1 = __expf(s1 - mx), e2 = __expf(s2 - mx);
    float inv = 1.f / (e0 + e1 + e2);
    float a0 = e0 * inv, a1 = e1 * inv, a2 = e2 * inv;
    size_t off = (size_t)n * 128 + c;
    ushort4 u0 = *(const ushort4*)(x0 + off);
    ushort4 u1 = *(const ushort4*)(x1 + off);
    ushort4 u2 = *(const ushort4*)(x2 + off);
    ushort4 o;
    o.x = f2bf(a0*bf2f(u0.x) + a1*bf2f(u1.x) + a2*bf2f(u2.x));
    o.y = f2bf(a0*bf2f(u0.y) + a1*bf2f(u1.y) + a2*bf2f(u2.y));
    o.z = f2bf(a0*bf2f(u0.z) + a1*bf2f(u1.z) + a2*bf2f(u2.z));
    o.w = f2bf(a0*bf2f(u0.w) + a1*bf2f(u1.w) + a2*bf2f(u2.w));
    *(ushort4*)(jkb + off) = o;
}

__global__ void final_out_k(const float* __restrict__ h2, const float* __restrict__ ow,
                            const float* __restrict__ ob, float* __restrict__ out, int N_) {
    int n = blockIdx.x * 256 + threadIdx.x;
    if (n >= N_) return;
    float l[6];
    #pragma unroll
    for (int j = 0; j < 6; ++j) l[j] = ob[j];
    for (int c = 0; c < 64; c += 4) {
        float4 h4 = *(const float4*)(h2 + (size_t)n * 64 + c);
        #pragma unroll
        for (int j = 0; j < 6; ++j) {
            l[j] += h4.x * ow[j*64 + c + 0] + h4.y * ow[j*64 + c + 1]
                  + h4.z * ow[j*64 + c + 2] + h4.w * ow[j*64 + c + 3];
        }
    }
    float mx = l[0];
    #pragma unroll
    for (int j = 1; j < 6; ++j) mx = fmaxf(mx, l[j]);
    float se = 0.f;
    #pragma unroll
    for (int j = 0; j < 6; ++j) se += __expf(l[j] - mx);
    float ls = logf(se) + mx;
    #pragma unroll
    for (int j = 0; j < 6; ++j) out[(size_t)n * 6 + j] = l[j] - ls;
}

// ---------------------------------------------------------------- launch
extern "C" void kernel_launch(void* const* d_in, const int* in_sizes, int n_in,
                              void* d_out, int out_size, void* d_ws, size_t ws_size,
                              hipStream_t stream) {
    const float* x   = (const float*)d_in[0];
    const int*   ei  = (const int*)d_in[1];
    const float* W1  = (const float*)d_in[2];
    const float* a1s = (const float*)d_in[3];
    const float* a1d = (const float*)d_in[4];
    const float* b1  = (const float*)d_in[5];
    const float* Ws  = (const float*)d_in[6];
    const float* ass = (const float*)d_in[7];
    const float* asd = (const float*)d_in[8];
    const float* bs  = (const float*)d_in[9];
    const float* Wih = (const float*)d_in[10];
    const float* Whh = (const float*)d_in[11];
    const float* bih = (const float*)d_in[12];
    const float* bhh = (const float*)d_in[13];
    const float* jkw = (const float*)d_in[14];
    const float* jkb_b = (const float*)d_in[15];
    const float* l1w = (const float*)d_in[16];
    const float* l1b = (const float*)d_in[17];
    const float* l2w = (const float*)d_in[18];
    const float* l2b = (const float*)d_in[19];
    const float* ow  = (const float*)d_in[20];
    const float* ob  = (const float*)d_in[21];
    float* out = (float*)d_out;

    int Nn = in_sizes[0] / 128;
    int E  = in_sizes[1] / 2;
    int ET = E + Nn;
    size_t Np = ((size_t)Nn + 63) & ~(size_t)63;
    size_t Fp = Np * 128;

    float* w = (float*)d_ws;
    float* es    = w;                    // [2Nn]
    float* ed    = es + 2*Nn;            // [2Nn]
    float* score = ed + 2*Nn;            // [6Nn] (two per-dir [3Nn] buffers)
    float* bsum  = score + 6*Nn;         // [1024]
    float* h2    = bsum + 1024;          // [Nn*64]
    unsigned short* xb   = (unsigned short*)(h2 + (size_t)Nn*64);  // [Fp]
    unsigned short* xpb  = xb + Fp;      // [Fp]; reused as jkb
    unsigned short* xsb0 = xpb + Fp;
    unsigned short* xsb1 = xsb0 + Fp;
    unsigned short* xsb2 = xsb1 + Fp;
    unsigned short* h1b  = xsb2 + Fp;    // [Fp] (only Nn*64 used)
    unsigned short* Wp   = h1b + Fp;     // [2*512*256]
    unsigned short* wb   = Wp + 2*512*256; // [69632]
    int* deg     = (int*)(wb + 69632);
    int* row_ptr = deg + Nn;
    int* cursor  = row_ptr + Nn;
    int* part    = cursor + Nn;          // [64]
    int* csr_src = part + 64;            // [ET]
    unsigned short* jkb = xpb;

    // ---- CSR by destination (edges identical for all 3 layers)
    int nb1 = CDIV(Nn, 1024);
    zero_i32<<<CDIV(Nn, 256), 256, 0, stream>>>(deg, Nn);
    hist_k<<<CDIV(ET, 256), 256, 0, stream>>>(ei, E, ET, deg);
    scan1_k<<<nb1, 256, 0, stream>>>(deg, row_ptr, part, Nn);
    scan2_k<<<1, 64, 0, stream>>>(part, nb1);
    scan3_k<<<CDIV(Nn, 256), 256, 0, stream>>>(part, row_ptr, cursor, Nn);
    fill_k<<<CDIV(ET, 256), 256, 0, stream>>>(ei, E, ET, cursor, csr_src);

    // ---- fused packs / converts
    int nprep = 262144 + 69632 + Nn * 128;
    prep_k<<<CDIV(nprep, 256), 256, 0, stream>>>(Wih, Whh, bih, bhh, Wp, bsum,
                                                 W1, Ws, l1w, l2w, wb, x, xb, Nn * 128);

    unsigned short* xsb_arr[3] = {xsb0, xsb1, xsb2};
    int gblk = CDIV(Nn, 64);

    for (int l = 0; l < 3; ++l) {
        const float* asl = (l == 0) ? a1s : ass + (size_t)(l-1) * 128;
        const float* adl = (l == 0) ? a1d : asd + (size_t)(l-1) * 128;
        const float* bl  = (l == 0) ? b1  : bs  + (size_t)(l-1) * 128;
        const unsigned short* Ain = (l == 0) ? xb : xsb_arr[l-1];
        const unsigned short* Wbl = wb + (size_t)l * 16384;
        gemm_mfma_k<8,128,128,false,true,true><<<gblk, 256, 0, stream>>>(
            Ain, Ain, 128, Wbl, nullptr, xpb, nullptr, asl, adl, es, ed, Nn);
        gat_agg_k<<<CDIV(Nn, 16), 256, 0, stream>>>(csr_src, row_ptr, deg, xpb, es, ed, bl,
                                                    xsb_arr[l], Nn, l > 0);
    }

    int ntiles = CDIV(Nn, 32);
    int gx = ntiles < 128 ? ntiles : 128;
    lstm_all_k<<<dim3(gx, 2), 512, 0, stream>>>(xsb0, xsb1, xsb2, Wp, bsum, jkw, score, Nn, ntiles);

    jk_combine_k<<<CDIV(Nn*32, 256), 256, 0, stream>>>(score, score + (size_t)3*Nn, jkb_b,
                                                       xsb0, xsb1, xsb2, jkb, Nn);
    gemm_mfma_k<4,128,128,true,false,true><<<gblk, 256, 0, stream>>>(
        jkb, jkb, 128, wb + 49152, l1b, h1b, nullptr, nullptr, nullptr, nullptr, nullptr, Nn);
    gemm_mfma_k<4,192,64,true,false,false><<<gblk, 256, 0, stream>>>(
        h1b, xb, 128, wb + 57344, l2b, nullptr, h2, nullptr, nullptr, nullptr, nullptr, Nn);
    final_out_k<<<CDIV(Nn, 256), 256, 0, stream>>>(h2, ow, ob, out, Nn);
}

// Round 18
// 524.878 us; speedup vs baseline: 1.1957x; 1.0504x over previous
//
#include <hip/hip_runtime.h>
#include <math.h>

#define CDIV(a,b) (((a)+(b)-1)/(b))

typedef __attribute__((ext_vector_type(8))) short bfrag;
typedef __attribute__((ext_vector_type(4))) float ffrag;

__device__ inline unsigned short f2bf(float f) {
    unsigned int u = __float_as_uint(f);
    return (unsigned short)((u + 0x7fffu + ((u >> 16) & 1u)) >> 16);
}
__device__ inline float bf2f(unsigned short u) {
    return __uint_as_float(((unsigned int)u) << 16);
}
__device__ inline float sigf(float x) {
    return __builtin_amdgcn_rcpf(1.f + __expf(-x));
}
__device__ inline float tanhfast(float x) {
    float t = __expf(-2.f * fabsf(x));
    float r = (1.f - t) * __builtin_amdgcn_rcpf(1.f + t);
    return copysignf(r, x);
}
// swizzled element offset into a [R][128] bf16 LDS tile (16B-chunk XOR swizzle)
__device__ inline int hoff(int row, int k) {
    int sw = ((k >> 3) ^ row) & 15;
    return row * 128 + sw * 8 + (k & 7);
}

// ---------------------------------------------------------------- utils
__global__ void zero_i32(int* __restrict__ p, int n) {
    int i = blockIdx.x * 256 + threadIdx.x;
    if (i < n) p[i] = 0;
}

// fused prep: LSTM W pack + bsum, dense-W pack, x->bf16 convert
__global__ void prep_k(const float* __restrict__ Wih, const float* __restrict__ Whh,
                       const float* __restrict__ bih, const float* __restrict__ bhh,
                       unsigned short* __restrict__ Wp, float* __restrict__ bsum,
                       const float* __restrict__ W1, const float* __restrict__ Ws,
                       const float* __restrict__ l1w, const float* __restrict__ l2w,
                       unsigned short* __restrict__ wb,
                       const float* __restrict__ x, unsigned short* __restrict__ xb, int nx) {
    int i = blockIdx.x * 256 + threadIdx.x;
    if (i < 1024) bsum[i] = bih[i] + bhh[i];
    if (i < 262144) {
        int k = i & 255, j = (i >> 8) & 511, d = i >> 17;
        float v = (k < 128) ? Wih[((size_t)d * 512 + j) * 128 + k]
                            : Whh[((size_t)d * 512 + j) * 128 + (k - 128)];
        Wp[i] = f2bf(v);
        return;
    }
    int i2 = i - 262144;
    if (i2 < 69632) {
        float v;
        if (i2 < 16384)      v = W1[i2];
        else if (i2 < 49152) v = Ws[i2 - 16384];
        else if (i2 < 57344) v = l1w[i2 - 49152];
        else                 v = l2w[i2 - 57344];
        wb[i2] = f2bf(v);
        return;
    }
    int i3 = i2 - 69632;
    if (i3 < nx) xb[i3] = f2bf(x[i3]);
}

// ---------------------------------------------------------------- CSR build
__global__ void hist_k(const int* __restrict__ ei, int E, int ET, int* __restrict__ deg) {
    int e = blockIdx.x * 256 + threadIdx.x;
    if (e >= ET) return;
    int d = (e < E) ? ei[E + e] : e - E;
    atomicAdd(deg + d, 1);
}

__global__ __launch_bounds__(256)
void scan1_k(const int* __restrict__ deg, int* __restrict__ row_ptr,
             int* __restrict__ part, int Nn) {
    __shared__ int ls[256];
    int t = threadIdx.x;
    int base = blockIdx.x * 1024 + t * 4;
    int v[4];
    #pragma unroll
    for (int j = 0; j < 4; ++j) v[j] = (base + j < Nn) ? deg[base + j] : 0;
    int s = v[0] + v[1] + v[2] + v[3];
    ls[t] = s;
    __syncthreads();
    for (int off = 1; off < 256; off <<= 1) {
        int o = (t >= off) ? ls[t - off] : 0;
        __syncthreads();
        ls[t] += o;
        __syncthreads();
    }
    int run = ls[t] - s;
    if (t == 255) part[blockIdx.x] = ls[255];
    #pragma unroll
    for (int j = 0; j < 4; ++j) {
        if (base + j < Nn) row_ptr[base + j] = run;
        run += v[j];
    }
}
__global__ void scan2_k(int* __restrict__ part, int nb) {
    int lane = threadIdx.x;
    int v = (lane < nb) ? part[lane] : 0;
    int orig = v;
    for (int off = 1; off < 64; off <<= 1) {
        int o = __shfl_up(v, off);
        if (lane >= off) v += o;
    }
    if (lane < nb) part[lane] = v - orig;
}
__global__ void scan3_k(const int* __restrict__ part, int* __restrict__ row_ptr,
                        int* __restrict__ cursor, int Nn) {
    int i = blockIdx.x * 256 + threadIdx.x;
    if (i >= Nn) return;
    int v = row_ptr[i] + part[i >> 10];
    row_ptr[i] = v;
    cursor[i] = v;
}

__global__ void fill_k(const int* __restrict__ ei, int E, int ET,
                       int* __restrict__ cursor, int* __restrict__ csr_src) {
    int e = blockIdx.x * 256 + threadIdx.x;
    if (e >= ET) return;
    int s, d;
    if (e < E) { s = ei[e]; d = ei[E + e]; } else { s = e - E; d = s; }
    int pos = atomicAdd(cursor + d, 1);
    csr_src[pos] = s;
}

// ---------------------------------------------------------------- MFMA GEMM (layer linears)
template<int NT, int K, int K1, bool RELU, bool FUSE, bool BFOUT>
__global__ __launch_bounds__(256)
void gemm_mfma_k(const unsigned short* __restrict__ A1, const unsigned short* __restrict__ A2,
                 int ldA2, const unsigned short* __restrict__ Wb, const float* __restrict__ bias,
                 unsigned short* __restrict__ Cb, float* __restrict__ Cf,
                 const float* __restrict__ asl, const float* __restrict__ adl,
                 float* __restrict__ es, float* __restrict__ ed, int M)
{
    int tid = threadIdx.x;
    int wv = tid >> 6, lane = tid & 63;
    int col = lane & 15, kg = lane >> 4;
    int row0 = blockIdx.x * 64 + wv * 16;
    int mrow = row0 + col;
    bool mok = mrow < M;

    ffrag acc[NT];
    #pragma unroll
    for (int t = 0; t < NT; ++t) acc[t] = (ffrag){0.f, 0.f, 0.f, 0.f};

    #pragma unroll
    for (int ks = 0; ks < K / 32; ++ks) {
        int kk = ks * 32 + kg * 8;
        bfrag a = (bfrag){0,0,0,0,0,0,0,0};
        if (mok) {
            if (kk < K1) a = *(const bfrag*)(A1 + (size_t)mrow * K1 + kk);
            else         a = *(const bfrag*)(A2 + (size_t)mrow * ldA2 + (kk - K1));
        }
        #pragma unroll
        for (int t = 0; t < NT; ++t) {
            bfrag b = *(const bfrag*)(Wb + (size_t)(t * 16 + col) * K + kk);
            acc[t] = __builtin_amdgcn_mfma_f32_16x16x32_bf16(a, b, acc[t], 0, 0, 0);
        }
    }

    #pragma unroll
    for (int r = 0; r < 4; ++r) {
        int n = row0 + kg * 4 + r;
        bool ok = n < M;
        float e0 = 0.f, e1 = 0.f, d0 = 0.f, d1 = 0.f;
        #pragma unroll
        for (int t = 0; t < NT; ++t) {
            float v = acc[t][r];
            if (FUSE) {
                int ch = t * 16 + col;
                if (t < NT / 2) { e0 = fmaf(v, asl[ch], e0); d0 = fmaf(v, adl[ch], d0); }
                else            { e1 = fmaf(v, asl[ch], e1); d1 = fmaf(v, adl[ch], d1); }
            }
            if (bias) v += bias[t * 16 + col];
            if (RELU) v = fmaxf(v, 0.f);
            if (ok) {
                if (BFOUT) Cb[(size_t)n * (NT * 16) + t * 16 + col] = f2bf(v);
                else       Cf[(size_t)n * (NT * 16) + t * 16 + col] = v;
            }
        }
        if (FUSE) {
            #pragma unroll
            for (int mk = 1; mk < 16; mk <<= 1) {
                e0 += __shfl_xor(e0, mk); e1 += __shfl_xor(e1, mk);
                d0 += __shfl_xor(d0, mk); d1 += __shfl_xor(d1, mk);
            }
            if (col == 0 && ok) {
                es[n * 2] = e0; es[n * 2 + 1] = e1;
                ed[n * 2] = d0; ed[n * 2 + 1] = d1;
            }
        }
    }
}

// ---------------------------------------------------------------- GAT aggregate (r16-proven)
__global__ __launch_bounds__(256)
void gat_agg_k(const int* __restrict__ csr_src, const int* __restrict__ row_ptr,
               const int* __restrict__ deg,
               const unsigned short* __restrict__ xpb, const float* __restrict__ es,
               const float* __restrict__ ed, const float* __restrict__ bias,
               unsigned short* __restrict__ out, int Nn, int relu)
{
    int tid = threadIdx.x;
    int l16 = tid & 15;
    int n = blockIdx.x * 16 + (tid >> 4);
    if (n >= Nn) return;
    int beg = row_ptr[n];
    int dn = deg[n];
    float2 edv = *(const float2*)(ed + n * 2);

    int   src_c = 0;
    float z0_c = 0.f, z1_c = 0.f;
    float m0 = -3e38f, m1 = -3e38f, s0 = 0.f, s1 = 0.f;
    for (int i = l16; i < dn; i += 16) {
        int s = csr_src[beg + i];
        float2 e2 = *(const float2*)(es + s * 2);
        float z0 = e2.x + edv.x; z0 = z0 > 0.f ? z0 : 0.2f * z0;
        float z1 = e2.y + edv.y; z1 = z1 > 0.f ? z1 : 0.2f * z1;
        if (i == l16) { src_c = s; z0_c = z0; z1_c = z1; }
        float nm0 = fmaxf(m0, z0);
        s0 = s0 * __expf(m0 - nm0) + __expf(z0 - nm0); m0 = nm0;
        float nm1 = fmaxf(m1, z1);
        s1 = s1 * __expf(m1 - nm1) + __expf(z1 - nm1); m1 = nm1;
    }
    #pragma unroll
    for (int off = 8; off; off >>= 1) {
        float om0 = __shfl_xor(m0, off), os0 = __shfl_xor(s0, off);
        float nm0 = fmaxf(m0, om0);
        s0 = s0 * __expf(m0 - nm0) + os0 * __expf(om0 - nm0); m0 = nm0;
        float om1 = __shfl_xor(m1, off), os1 = __shfl_xor(s1, off);
        float nm1 = fmaxf(m1, om1);
        s1 = s1 * __expf(m1 - nm1) + os1 * __expf(om1 - nm1); m1 = nm1;
    }
    float inv0 = 1.f / s0, inv1 = 1.f / s1;

    float a0_c = __expf(z0_c - m0) * inv0;
    float a1_c = __expf(z1_c - m1) * inv1;

    int gbase = (tid & 63) & ~15;
    float acc[8] = {};
    for (int i = 0; i < dn; ++i) {
        int s; float aw;
        if (i < 16) {               // uniform branch; shuffles OUTSIDE any lane split
            int sl = gbase + i;
            int   sv = __shfl(src_c, sl);
            float A0 = __shfl(a0_c, sl);
            float A1 = __shfl(a1_c, sl);
            s = sv;
            aw = (l16 < 8) ? A0 : A1;
        } else {
            s = csr_src[beg + i];
            float2 e2 = *(const float2*)(es + s * 2);
            float z0 = e2.x + edv.x; z0 = z0 > 0.f ? z0 : 0.2f * z0;
            float z1 = e2.y + edv.y; z1 = z1 > 0.f ? z1 : 0.2f * z1;
            float aw0 = __expf(z0 - m0) * inv0;
            float aw1 = __expf(z1 - m1) * inv1;
            aw = (l16 < 8) ? aw0 : aw1;
        }
        bfrag v = *(const bfrag*)(xpb + (size_t)s * 128 + l16 * 8);
        #pragma unroll
        for (int j = 0; j < 8; ++j)
            acc[j] = fmaf(bf2f((unsigned short)v[j]), aw, acc[j]);
    }

    float4 b0 = *(const float4*)(bias + l16 * 8);
    float4 b1 = *(const float4*)(bias + l16 * 8 + 4);
    float vb[8] = {b0.x, b0.y, b0.z, b0.w, b1.x, b1.y, b1.z, b1.w};
    unsigned int wds[4];
    #pragma unroll
    for (int j = 0; j < 4; ++j) {
        float v0 = acc[2*j]   + vb[2*j];
        float v1 = acc[2*j+1] + vb[2*j+1];
        if (relu) { v0 = fmaxf(v0, 0.f); v1 = fmaxf(v1, 0.f); }
        wds[j] = (unsigned int)f2bf(v0) | ((unsigned int)f2bf(v1) << 16);
    }
    *(uint4*)(out + (size_t)n * 128 + l16 * 8) = make_uint4(wds[0], wds[1], wds[2], wds[3]);
}

// ---------------------------------------------------------------- fused biLSTM (r16-proven)
__global__ __launch_bounds__(512)
void lstm_all_k(const unsigned short* __restrict__ X0, const unsigned short* __restrict__ X1,
                const unsigned short* __restrict__ X2,
                const unsigned short* __restrict__ WpB, const float* __restrict__ bsumB,
                const float* __restrict__ jkw, float* __restrict__ score, int Nn, int ntiles)
{
    __shared__ unsigned short h_lds[2][32 * 128];
    __shared__ float sc_s[96];
    int dir = blockIdx.y;
    const unsigned short* Xs0 = dir ? X2 : X0;
    const unsigned short* Xs2 = dir ? X0 : X2;
    const unsigned short* Wp = WpB + (size_t)dir * 512 * 256;
    const float* bsum = bsumB + dir * 512;
    const float* wsc = jkw + dir * 128;
    float* scD = score + (size_t)dir * 3 * Nn;

    int tid = threadIdx.x;
    int wv = tid >> 6, lane = tid & 63;
    int col = lane & 15, kg = lane >> 4;
    int t0 = dir ? 2 : 0;
    int kch = 16 * wv + col;
    float bi = bsum[kch], bf_ = bsum[128 + kch];
    float bg = bsum[256 + kch], bo = bsum[384 + kch];
    float wk = wsc[kch];

    bfrag wreg[4][8];
    #pragma unroll
    for (int g = 0; g < 4; ++g) {
        const unsigned short* wrow = Wp + (size_t)(16 * (8 * g + wv) + col) * 256;
        #pragma unroll
        for (int ks = 0; ks < 8; ++ks)
            wreg[g][ks] = *(const bfrag*)(wrow + ks * 32 + kg * 8);
    }

    for (int tile = blockIdx.x; tile < ntiles; tile += gridDim.x) {
        int node0 = tile * 32;
        float c[2][4] = {};
        if (tid < 96) sc_s[tid] = 0.f;
        __syncthreads();

        #pragma unroll
        for (int i = 0; i < 3; ++i) {
            const unsigned short* Xt = (i == 0) ? Xs0 : ((i == 1) ? X1 : Xs2);
            const unsigned short* h_rd = h_lds[(i + 1) & 1];
            unsigned short* h_wr = h_lds[i & 1];

            ffrag acc[2][4];
            #pragma unroll
            for (int nt = 0; nt < 2; ++nt)
                #pragma unroll
                for (int g = 0; g < 4; ++g) acc[nt][g] = (ffrag){0.f, 0.f, 0.f, 0.f};

            #pragma unroll
            for (int ks = 0; ks < 4; ++ks) {
                int kk = ks * 32 + kg * 8;
                bfrag a0 = *(const bfrag*)(Xt + (size_t)(node0 + col) * 128 + kk);
                bfrag a1 = *(const bfrag*)(Xt + (size_t)(node0 + 16 + col) * 128 + kk);
                #pragma unroll
                for (int g = 0; g < 4; ++g) {
                    acc[0][g] = __builtin_amdgcn_mfma_f32_16x16x32_bf16(a0, wreg[g][ks], acc[0][g], 0, 0, 0);
                    acc[1][g] = __builtin_amdgcn_mfma_f32_16x16x32_bf16(a1, wreg[g][ks], acc[1][g], 0, 0, 0);
                }
            }

            if (i > 0) {
                #pragma unroll
                for (int ks = 4; ks < 8; ++ks) {
                    int kh = (ks - 4) * 32 + kg * 8;
                    bfrag ah0 = *(const bfrag*)&h_rd[hoff(col, kh)];
                    bfrag ah1 = *(const bfrag*)&h_rd[hoff(16 + col, kh)];
                    #pragma unroll
                    for (int g = 0; g < 4; ++g) {
                        acc[0][g] = __builtin_amdgcn_mfma_f32_16x16x32_bf16(ah0, wreg[g][ks], acc[0][g], 0, 0, 0);
                        acc[1][g] = __builtin_amdgcn_mfma_f32_16x16x32_bf16(ah1, wreg[g][ks], acc[1][g], 0, 0, 0);
                    }
                }
            }

            #pragma unroll
            for (int nt = 0; nt < 2; ++nt) {
                #pragma unroll
                for (int r = 0; r < 4; ++r) {
                    float gi = acc[nt][0][r] + bi;
                    float gf = acc[nt][1][r] + bf_;
                    float gg = acc[nt][2][r] + bg;
                    float go = acc[nt][3][r] + bo;
                    float si = sigf(gi);
                    float sf = sigf(gf);
                    float so = sigf(go);
                    float tg = tanhfast(gg);
                    float cn = sf * c[nt][r] + si * tg;
                    float hn = so * tanhfast(cn);
                    c[nt][r] = cn;
                    int nl = nt * 16 + kg * 4 + r;
                    h_wr[hoff(nl, kch)] = f2bf(hn);
                    float v = hn * wk;
                    #pragma unroll
                    for (int mk = 1; mk < 16; mk <<= 1) v += __shfl_xor(v, mk);
                    if (col == 0) atomicAdd(&sc_s[i * 32 + nl], v);
                }
            }
            __syncthreads();
        }

        if (tid < 96) {
            int ii = tid >> 5, nl = tid & 31;
            int t = (ii == 0) ? t0 : ((ii == 1) ? 1 : (2 - t0));
            int n = node0 + nl;
            if (n < Nn) scD[(size_t)t * Nn + n] = sc_s[tid];
        }
        __syncthreads();
    }
}

// ---------------------------------------------------------------- fused head (r17 + ow-load fix)
__global__ __launch_bounds__(256)
void head_k(const float* __restrict__ scA, const float* __restrict__ scB,
            const float* __restrict__ jkbias,
            const unsigned short* __restrict__ x0, const unsigned short* __restrict__ x1,
            const unsigned short* __restrict__ x2, const unsigned short* __restrict__ xb,
            const unsigned short* __restrict__ wb,
            const float* __restrict__ l1b, const float* __restrict__ l2b,
            const float* __restrict__ ow, const float* __restrict__ ob,
            float* __restrict__ out, int Nn)
{
    __shared__ unsigned short jk_lds[64][136];  // 272B rows: 16B-aligned, 2-way banks
    __shared__ unsigned short h1_lds[64][72];   // 144B rows
    __shared__ float h2_lds[64][68];
    __shared__ float al_lds[64][4];
    __shared__ float ow_lds[384];
    __shared__ float ob_lds[8];

    int tid = threadIdx.x;
    int node0 = blockIdx.x * 64;
    int wv = tid >> 6, lane = tid & 63;
    int col = lane & 15, kg = lane >> 4;

    // r17 BUG FIX: block has 256 threads but ow has 384 elements — the old
    // `if (tid < 384)` guard left ow_lds[256..383] uninitialized (classes 4-5
    // garbage, absmax 381). Strided loop covers all 384.
    for (int i = tid; i < 384; i += 256) ow_lds[i] = ow[i];
    if (tid < 6) ob_lds[tid] = ob[tid];

    // JK alphas (one thread per node)
    if (tid < 64) {
        int n = node0 + tid;
        float b = jkbias[0];
        float s0 = 0.f, s1 = 0.f, s2 = 0.f;
        if (n < Nn) {
            s0 = b + scA[n] + scB[n];
            s1 = b + scA[Nn + n] + scB[Nn + n];
            s2 = b + scA[2 * Nn + n] + scB[2 * Nn + n];
        }
        float mx = fmaxf(s0, fmaxf(s1, s2));
        float e0 = __expf(s0 - mx), e1 = __expf(s1 - mx), e2 = __expf(s2 - mx);
        float inv = 1.f / (e0 + e1 + e2);
        al_lds[tid][0] = e0 * inv; al_lds[tid][1] = e1 * inv; al_lds[tid][2] = e2 * inv;
    }
    __syncthreads();

    // jk tile into LDS: thread -> node tid>>2, 32 channels at (tid&3)*32
    {
        int nl = tid >> 2;
        int c0 = (tid & 3) * 32;
        float a0 = al_lds[nl][0], a1 = al_lds[nl][1], a2 = al_lds[nl][2];
        size_t base = (size_t)(node0 + nl) * 128 + c0;   // xsb buffers are Np-padded: safe
        #pragma unroll
        for (int ch = 0; ch < 4; ++ch) {
            bfrag u0 = *(const bfrag*)(x0 + base + ch * 8);
            bfrag u1 = *(const bfrag*)(x1 + base + ch * 8);
            bfrag u2 = *(const bfrag*)(x2 + base + ch * 8);
            #pragma unroll
            for (int j = 0; j < 8; ++j) {
                float v = a0 * bf2f((unsigned short)u0[j]) + a1 * bf2f((unsigned short)u1[j])
                        + a2 * bf2f((unsigned short)u2[j]);
                jk_lds[nl][c0 + ch * 8 + j] = f2bf(v);
            }
        }
    }
    __syncthreads();

    // h1 = relu(jk @ l1w^T), K=128, 64 out ch
    {
        const unsigned short* l1w = wb + 49152;
        ffrag acc[4];
        #pragma unroll
        for (int t = 0; t < 4; ++t) acc[t] = (ffrag){0.f, 0.f, 0.f, 0.f};
        #pragma unroll
        for (int ks = 0; ks < 4; ++ks) {
            int kk = ks * 32 + kg * 8;
            bfrag a = *(const bfrag*)&jk_lds[wv * 16 + col][kk];
            #pragma unroll
            for (int t = 0; t < 4; ++t) {
                bfrag b = *(const bfrag*)(l1w + (size_t)(t * 16 + col) * 128 + kk);
                acc[t] = __builtin_amdgcn_mfma_f32_16x16x32_bf16(a, b, acc[t], 0, 0, 0);
            }
        }
        #pragma unroll
        for (int t = 0; t < 4; ++t) {
            float bb = l1b[t * 16 + col];
            #pragma unroll
            for (int r = 0; r < 4; ++r) {
                float v = fmaxf(acc[t][r] + bb, 0.f);
                h1_lds[wv * 16 + kg * 4 + r][t * 16 + col] = f2bf(v);
            }
        }
    }
    __syncthreads();

    // h2 = relu([h1 | x] @ l2w^T), K=192 (64 LDS + 128 global xb)
    {
        const unsigned short* l2w = wb + 57344;
        ffrag acc[4];
        #pragma unroll
        for (int t = 0; t < 4; ++t) acc[t] = (ffrag){0.f, 0.f, 0.f, 0.f};
        #pragma unroll
        for (int ks = 0; ks < 6; ++ks) {
            int kk = ks * 32 + kg * 8;
            bfrag a;
            if (kk < 64) a = *(const bfrag*)&h1_lds[wv * 16 + col][kk];
            else         a = *(const bfrag*)(xb + (size_t)(node0 + wv * 16 + col) * 128 + (kk - 64));
            #pragma unroll
            for (int t = 0; t < 4; ++t) {
                bfrag b = *(const bfrag*)(l2w + (size_t)(t * 16 + col) * 192 + kk);
                acc[t] = __builtin_amdgcn_mfma_f32_16x16x32_bf16(a, b, acc[t], 0, 0, 0);
            }
        }
        #pragma unroll
        for (int t = 0; t < 4; ++t) {
            float bb = l2b[t * 16 + col];
            #pragma unroll
            for (int r = 0; r < 4; ++r)
                h2_lds[wv * 16 + kg * 4 + r][t * 16 + col] = fmaxf(acc[t][r] + bb, 0.f);
        }
    }
    __syncthreads();

    // logits + log_softmax (one lane per node)
    if (tid < 64) {
        int n = node0 + tid;
        if (n < Nn) {
            float l[6];
            #pragma unroll
            for (int j = 0; j < 6; ++j) l[j] = ob_lds[j];
            for (int cch = 0; cch < 64; ++cch) {
                float h = h2_lds[tid][cch];
                #pragma unroll
                for (int j = 0; j < 6; ++j) l[j] = fmaf(h, ow_lds[j * 64 + cch], l[j]);
            }
            float mx = l[0];
            #pragma unroll
            for (int j = 1; j < 6; ++j) mx = fmaxf(mx, l[j]);
            float se = 0.f;
            #pragma unroll
            for (int j = 0; j < 6; ++j) se += __expf(l[j] - mx);
            float ls = logf(se) + mx;
            #pragma unroll
            for (int j = 0; j < 6; ++j) out[(size_t)n * 6 + j] = l[j] - ls;
        }
    }
}

// ---------------------------------------------------------------- launch
extern "C" void kernel_launch(void* const* d_in, const int* in_sizes, int n_in,
                              void* d_out, int out_size, void* d_ws, size_t ws_size,
                              hipStream_t stream) {
    const float* x   = (const float*)d_in[0];
    const int*   ei  = (const int*)d_in[1];
    const float* W1  = (const float*)d_in[2];
    const float* a1s = (const float*)d_in[3];
    const float* a1d = (const float*)d_in[4];
    const float* b1  = (const float*)d_in[5];
    const float* Ws  = (const float*)d_in[6];
    const float* ass = (const float*)d_in[7];
    const float* asd = (const float*)d_in[8];
    const float* bs  = (const float*)d_in[9];
    const float* Wih = (const float*)d_in[10];
    const float* Whh = (const float*)d_in[11];
    const float* bih = (const float*)d_in[12];
    const float* bhh = (const float*)d_in[13];
    const float* jkw = (const float*)d_in[14];
    const float* jkb_b = (const float*)d_in[15];
    const float* l1w = (const float*)d_in[16];
    const float* l1b = (const float*)d_in[17];
    const float* l2w = (const float*)d_in[18];
    const float* l2b = (const float*)d_in[19];
    const float* ow  = (const float*)d_in[20];
    const float* ob  = (const float*)d_in[21];
    float* out = (float*)d_out;

    int Nn = in_sizes[0] / 128;
    int E  = in_sizes[1] / 2;
    int ET = E + Nn;
    size_t Np = ((size_t)Nn + 63) & ~(size_t)63;
    size_t Fp = Np * 128;

    float* w = (float*)d_ws;
    float* es    = w;                    // [2Nn]
    float* ed    = es + 2*Nn;            // [2Nn]
    float* score = ed + 2*Nn;            // [6Nn] (two per-dir [3Nn] buffers)
    float* bsum  = score + 6*Nn;         // [1024]
    float* h2    = bsum + 1024;          // [Nn*64] (unused now, kept for layout)
    unsigned short* xb   = (unsigned short*)(h2 + (size_t)Nn*64);  // [Fp]
    unsigned short* xpb  = xb + Fp;      // [Fp]
    unsigned short* xsb0 = xpb + Fp;
    unsigned short* xsb1 = xsb0 + Fp;
    unsigned short* xsb2 = xsb1 + Fp;
    unsigned short* h1b  = xsb2 + Fp;    // [Fp] (unused now)
    unsigned short* Wp   = h1b + Fp;     // [2*512*256]
    unsigned short* wb   = Wp + 2*512*256; // [69632]
    int* deg     = (int*)(wb + 69632);
    int* row_ptr = deg + Nn;
    int* cursor  = row_ptr + Nn;
    int* part    = cursor + Nn;          // [64]
    int* csr_src = part + 64;            // [ET]

    // ---- CSR by destination (edges identical for all 3 layers)
    int nb1 = CDIV(Nn, 1024);
    zero_i32<<<CDIV(Nn, 256), 256, 0, stream>>>(deg, Nn);
    hist_k<<<CDIV(ET, 256), 256, 0, stream>>>(ei, E, ET, deg);
    scan1_k<<<nb1, 256, 0, stream>>>(deg, row_ptr, part, Nn);
    scan2_k<<<1, 64, 0, stream>>>(part, nb1);
    scan3_k<<<CDIV(Nn, 256), 256, 0, stream>>>(part, row_ptr, cursor, Nn);
    fill_k<<<CDIV(ET, 256), 256, 0, stream>>>(ei, E, ET, cursor, csr_src);

    // ---- fused packs / converts
    int nprep = 262144 + 69632 + Nn * 128;
    prep_k<<<CDIV(nprep, 256), 256, 0, stream>>>(Wih, Whh, bih, bhh, Wp, bsum,
                                                 W1, Ws, l1w, l2w, wb, x, xb, Nn * 128);

    unsigned short* xsb_arr[3] = {xsb0, xsb1, xsb2};
    int gblk = CDIV(Nn, 64);

    for (int l = 0; l < 3; ++l) {
        const float* asl = (l == 0) ? a1s : ass + (size_t)(l-1) * 128;
        const float* adl = (l == 0) ? a1d : asd + (size_t)(l-1) * 128;
        const float* bl  = (l == 0) ? b1  : bs  + (size_t)(l-1) * 128;
        const unsigned short* Ain = (l == 0) ? xb : xsb_arr[l-1];
        const unsigned short* Wbl = wb + (size_t)l * 16384;
        gemm_mfma_k<8,128,128,false,true,true><<<gblk, 256, 0, stream>>>(
            Ain, Ain, 128, Wbl, nullptr, xpb, nullptr, asl, adl, es, ed, Nn);
        gat_agg_k<<<CDIV(Nn, 16), 256, 0, stream>>>(csr_src, row_ptr, deg, xpb, es, ed, bl,
                                                    xsb_arr[l], Nn, l > 0);
    }

    int ntiles = CDIV(Nn, 32);
    int gx = ntiles < 128 ? ntiles : 128;
    lstm_all_k<<<dim3(gx, 2), 512, 0, stream>>>(xsb0, xsb1, xsb2, Wp, bsum, jkw, score, Nn, ntiles);

    head_k<<<gblk, 256, 0, stream>>>(score, score + (size_t)3*Nn, jkb_b,
                                     xsb0, xsb1, xsb2, xb, wb, l1b, l2b, ow, ob, out, Nn);
}

// Round 19
// 518.319 us; speedup vs baseline: 1.2108x; 1.0127x over previous
//
#include <hip/hip_runtime.h>
#include <math.h>

#define CDIV(a,b) (((a)+(b)-1)/(b))

typedef __attribute__((ext_vector_type(8))) short bfrag;
typedef __attribute__((ext_vector_type(4))) float ffrag;

__device__ inline unsigned short f2bf(float f) {
    unsigned int u = __float_as_uint(f);
    return (unsigned short)((u + 0x7fffu + ((u >> 16) & 1u)) >> 16);
}
__device__ inline float bf2f(unsigned short u) {
    return __uint_as_float(((unsigned int)u) << 16);
}
__device__ inline float sigf(float x) {
    return __builtin_amdgcn_rcpf(1.f + __expf(-x));
}
__device__ inline float tanhfast(float x) {
    float t = __expf(-2.f * fabsf(x));
    float r = (1.f - t) * __builtin_amdgcn_rcpf(1.f + t);
    return copysignf(r, x);
}
// swizzled element offset into a [R][128] bf16 LDS tile (16B-chunk XOR swizzle)
__device__ inline int hoff(int row, int k) {
    int sw = ((k >> 3) ^ row) & 15;
    return row * 128 + sw * 8 + (k & 7);
}

// ---------------------------------------------------------------- fused hist + prep
// deg is pre-zeroed by hipMemsetAsync. One dispatch does the edge histogram AND
// all weight packs / x->bf16 conversion (independent index ranges; the atomic
// latency hides under the streaming pack bandwidth).
__global__ void hist_prep_k(const int* __restrict__ ei, int E, int ET, int* __restrict__ deg,
                            const float* __restrict__ Wih, const float* __restrict__ Whh,
                            const float* __restrict__ bih, const float* __restrict__ bhh,
                            unsigned short* __restrict__ Wp, float* __restrict__ bsum,
                            const float* __restrict__ W1, const float* __restrict__ Ws,
                            const float* __restrict__ l1w, const float* __restrict__ l2w,
                            unsigned short* __restrict__ wb,
                            const float* __restrict__ x, unsigned short* __restrict__ xb, int nx) {
    int i = blockIdx.x * 256 + threadIdx.x;
    if (i < ET) {
        int d = (i < E) ? ei[E + i] : i - E;
        atomicAdd(deg + d, 1);
    }
    if (i < 1024) bsum[i] = bih[i] + bhh[i];
    if (i < 262144) {
        int k = i & 255, j = (i >> 8) & 511, d = i >> 17;
        float v = (k < 128) ? Wih[((size_t)d * 512 + j) * 128 + k]
                            : Whh[((size_t)d * 512 + j) * 128 + (k - 128)];
        Wp[i] = f2bf(v);
        return;
    }
    int i2 = i - 262144;
    if (i2 < 69632) {
        float v;
        if (i2 < 16384)      v = W1[i2];
        else if (i2 < 49152) v = Ws[i2 - 16384];
        else if (i2 < 57344) v = l1w[i2 - 49152];
        else                 v = l2w[i2 - 57344];
        wb[i2] = f2bf(v);
        return;
    }
    int i3 = i2 - 69632;
    if (i3 < nx) xb[i3] = f2bf(x[i3]);
}

// ---------------------------------------------------------------- CSR scans
__global__ __launch_bounds__(256)
void scan1_k(const int* __restrict__ deg, int* __restrict__ row_ptr,
             int* __restrict__ part, int Nn) {
    __shared__ int ls[256];
    int t = threadIdx.x;
    int base = blockIdx.x * 1024 + t * 4;
    int v[4];
    #pragma unroll
    for (int j = 0; j < 4; ++j) v[j] = (base + j < Nn) ? deg[base + j] : 0;
    int s = v[0] + v[1] + v[2] + v[3];
    ls[t] = s;
    __syncthreads();
    for (int off = 1; off < 256; off <<= 1) {
        int o = (t >= off) ? ls[t - off] : 0;
        __syncthreads();
        ls[t] += o;
        __syncthreads();
    }
    int run = ls[t] - s;
    if (t == 255) part[blockIdx.x] = ls[255];
    #pragma unroll
    for (int j = 0; j < 4; ++j) {
        if (base + j < Nn) row_ptr[base + j] = run;
        run += v[j];
    }
}

// merged scan2+scan3: wave 0 re-scans the <=64 block partials (exclusive) into
// LDS, then all threads apply their chunk's offset. Kills the 1-block scan2
// dispatch (nb <= 64 holds for Nn <= 65536).
__global__ __launch_bounds__(256)
void scan23_k(const int* __restrict__ part, int nb, int* __restrict__ row_ptr,
              int* __restrict__ cursor, int Nn) {
    __shared__ int pre[64];
    int tid = threadIdx.x;
    if (tid < 64) {
        int v = (tid < nb) ? part[tid] : 0;
        int orig = v;
        #pragma unroll
        for (int off = 1; off < 64; off <<= 1) {
            int o = __shfl_up(v, off);
            if (tid >= off) v += o;
        }
        pre[tid] = v - orig;
    }
    __syncthreads();
    int i = blockIdx.x * 256 + tid;
    if (i >= Nn) return;
    int v = row_ptr[i] + pre[i >> 10];
    row_ptr[i] = v;
    cursor[i] = v;
}

__global__ void fill_k(const int* __restrict__ ei, int E, int ET,
                       int* __restrict__ cursor, int* __restrict__ csr_src) {
    int e = blockIdx.x * 256 + threadIdx.x;
    if (e >= ET) return;
    int s, d;
    if (e < E) { s = ei[e]; d = ei[E + e]; } else { s = e - E; d = s; }
    int pos = atomicAdd(cursor + d, 1);
    csr_src[pos] = s;
}

// ---------------------------------------------------------------- MFMA GEMM (layer linears)
template<int NT, int K, int K1, bool RELU, bool FUSE, bool BFOUT>
__global__ __launch_bounds__(256)
void gemm_mfma_k(const unsigned short* __restrict__ A1, const unsigned short* __restrict__ A2,
                 int ldA2, const unsigned short* __restrict__ Wb, const float* __restrict__ bias,
                 unsigned short* __restrict__ Cb, float* __restrict__ Cf,
                 const float* __restrict__ asl, const float* __restrict__ adl,
                 float* __restrict__ es, float* __restrict__ ed, int M)
{
    int tid = threadIdx.x;
    int wv = tid >> 6, lane = tid & 63;
    int col = lane & 15, kg = lane >> 4;
    int row0 = blockIdx.x * 64 + wv * 16;
    int mrow = row0 + col;
    bool mok = mrow < M;

    ffrag acc[NT];
    #pragma unroll
    for (int t = 0; t < NT; ++t) acc[t] = (ffrag){0.f, 0.f, 0.f, 0.f};

    #pragma unroll
    for (int ks = 0; ks < K / 32; ++ks) {
        int kk = ks * 32 + kg * 8;
        bfrag a = (bfrag){0,0,0,0,0,0,0,0};
        if (mok) {
            if (kk < K1) a = *(const bfrag*)(A1 + (size_t)mrow * K1 + kk);
            else         a = *(const bfrag*)(A2 + (size_t)mrow * ldA2 + (kk - K1));
        }
        #pragma unroll
        for (int t = 0; t < NT; ++t) {
            bfrag b = *(const bfrag*)(Wb + (size_t)(t * 16 + col) * K + kk);
            acc[t] = __builtin_amdgcn_mfma_f32_16x16x32_bf16(a, b, acc[t], 0, 0, 0);
        }
    }

    #pragma unroll
    for (int r = 0; r < 4; ++r) {
        int n = row0 + kg * 4 + r;
        bool ok = n < M;
        float e0 = 0.f, e1 = 0.f, d0 = 0.f, d1 = 0.f;
        #pragma unroll
        for (int t = 0; t < NT; ++t) {
            float v = acc[t][r];
            if (FUSE) {
                int ch = t * 16 + col;
                if (t < NT / 2) { e0 = fmaf(v, asl[ch], e0); d0 = fmaf(v, adl[ch], d0); }
                else            { e1 = fmaf(v, asl[ch], e1); d1 = fmaf(v, adl[ch], d1); }
            }
            if (bias) v += bias[t * 16 + col];
            if (RELU) v = fmaxf(v, 0.f);
            if (ok) {
                if (BFOUT) Cb[(size_t)n * (NT * 16) + t * 16 + col] = f2bf(v);
                else       Cf[(size_t)n * (NT * 16) + t * 16 + col] = v;
            }
        }
        if (FUSE) {
            #pragma unroll
            for (int mk = 1; mk < 16; mk <<= 1) {
                e0 += __shfl_xor(e0, mk); e1 += __shfl_xor(e1, mk);
                d0 += __shfl_xor(d0, mk); d1 += __shfl_xor(d1, mk);
            }
            if (col == 0 && ok) {
                es[n * 2] = e0; es[n * 2 + 1] = e1;
                ed[n * 2] = d0; ed[n * 2 + 1] = d1;
            }
        }
    }
}

// ---------------------------------------------------------------- GAT aggregate (r16-proven)
__global__ __launch_bounds__(256)
void gat_agg_k(const int* __restrict__ csr_src, const int* __restrict__ row_ptr,
               const int* __restrict__ deg,
               const unsigned short* __restrict__ xpb, const float* __restrict__ es,
               const float* __restrict__ ed, const float* __restrict__ bias,
               unsigned short* __restrict__ out, int Nn, int relu)
{
    int tid = threadIdx.x;
    int l16 = tid & 15;
    int n = blockIdx.x * 16 + (tid >> 4);
    if (n >= Nn) return;
    int beg = row_ptr[n];
    int dn = deg[n];
    float2 edv = *(const float2*)(ed + n * 2);

    int   src_c = 0;
    float z0_c = 0.f, z1_c = 0.f;
    float m0 = -3e38f, m1 = -3e38f, s0 = 0.f, s1 = 0.f;
    for (int i = l16; i < dn; i += 16) {
        int s = csr_src[beg + i];
        float2 e2 = *(const float2*)(es + s * 2);
        float z0 = e2.x + edv.x; z0 = z0 > 0.f ? z0 : 0.2f * z0;
        float z1 = e2.y + edv.y; z1 = z1 > 0.f ? z1 : 0.2f * z1;
        if (i == l16) { src_c = s; z0_c = z0; z1_c = z1; }
        float nm0 = fmaxf(m0, z0);
        s0 = s0 * __expf(m0 - nm0) + __expf(z0 - nm0); m0 = nm0;
        float nm1 = fmaxf(m1, z1);
        s1 = s1 * __expf(m1 - nm1) + __expf(z1 - nm1); m1 = nm1;
    }
    #pragma unroll
    for (int off = 8; off; off >>= 1) {
        float om0 = __shfl_xor(m0, off), os0 = __shfl_xor(s0, off);
        float nm0 = fmaxf(m0, om0);
        s0 = s0 * __expf(m0 - nm0) + os0 * __expf(om0 - nm0); m0 = nm0;
        float om1 = __shfl_xor(m1, off), os1 = __shfl_xor(s1, off);
        float nm1 = fmaxf(m1, om1);
        s1 = s1 * __expf(m1 - nm1) + os1 * __expf(om1 - nm1); m1 = nm1;
    }
    float inv0 = 1.f / s0, inv1 = 1.f / s1;

    float a0_c = __expf(z0_c - m0) * inv0;
    float a1_c = __expf(z1_c - m1) * inv1;

    int gbase = (tid & 63) & ~15;
    float acc[8] = {};
    for (int i = 0; i < dn; ++i) {
        int s; float aw;
        if (i < 16) {               // uniform branch; shuffles OUTSIDE any lane split
            int sl = gbase + i;
            int   sv = __shfl(src_c, sl);
            float A0 = __shfl(a0_c, sl);
            float A1 = __shfl(a1_c, sl);
            s = sv;
            aw = (l16 < 8) ? A0 : A1;
        } else {
            s = csr_src[beg + i];
            float2 e2 = *(const float2*)(es + s * 2);
            float z0 = e2.x + edv.x; z0 = z0 > 0.f ? z0 : 0.2f * z0;
            float z1 = e2.y + edv.y; z1 = z1 > 0.f ? z1 : 0.2f * z1;
            float aw0 = __expf(z0 - m0) * inv0;
            float aw1 = __expf(z1 - m1) * inv1;
            aw = (l16 < 8) ? aw0 : aw1;
        }
        bfrag v = *(const bfrag*)(xpb + (size_t)s * 128 + l16 * 8);
        #pragma unroll
        for (int j = 0; j < 8; ++j)
            acc[j] = fmaf(bf2f((unsigned short)v[j]), aw, acc[j]);
    }

    float4 b0 = *(const float4*)(bias + l16 * 8);
    float4 b1 = *(const float4*)(bias + l16 * 8 + 4);
    float vb[8] = {b0.x, b0.y, b0.z, b0.w, b1.x, b1.y, b1.z, b1.w};
    unsigned int wds[4];
    #pragma unroll
    for (int j = 0; j < 4; ++j) {
        float v0 = acc[2*j]   + vb[2*j];
        float v1 = acc[2*j+1] + vb[2*j+1];
        if (relu) { v0 = fmaxf(v0, 0.f); v1 = fmaxf(v1, 0.f); }
        wds[j] = (unsigned int)f2bf(v0) | ((unsigned int)f2bf(v1) << 16);
    }
    *(uint4*)(out + (size_t)n * 128 + l16 * 8) = make_uint4(wds[0], wds[1], wds[2], wds[3]);
}

// ---------------------------------------------------------------- fused biLSTM (r16-proven)
__global__ __launch_bounds__(512)
void lstm_all_k(const unsigned short* __restrict__ X0, const unsigned short* __restrict__ X1,
                const unsigned short* __restrict__ X2,
                const unsigned short* __restrict__ WpB, const float* __restrict__ bsumB,
                const float* __restrict__ jkw, float* __restrict__ score, int Nn, int ntiles)
{
    __shared__ unsigned short h_lds[2][32 * 128];
    __shared__ float sc_s[96];
    int dir = blockIdx.y;
    const unsigned short* Xs0 = dir ? X2 : X0;
    const unsigned short* Xs2 = dir ? X0 : X2;
    const unsigned short* Wp = WpB + (size_t)dir * 512 * 256;
    const float* bsum = bsumB + dir * 512;
    const float* wsc = jkw + dir * 128;
    float* scD = score + (size_t)dir * 3 * Nn;

    int tid = threadIdx.x;
    int wv = tid >> 6, lane = tid & 63;
    int col = lane & 15, kg = lane >> 4;
    int t0 = dir ? 2 : 0;
    int kch = 16 * wv + col;
    float bi = bsum[kch], bf_ = bsum[128 + kch];
    float bg = bsum[256 + kch], bo = bsum[384 + kch];
    float wk = wsc[kch];

    bfrag wreg[4][8];
    #pragma unroll
    for (int g = 0; g < 4; ++g) {
        const unsigned short* wrow = Wp + (size_t)(16 * (8 * g + wv) + col) * 256;
        #pragma unroll
        for (int ks = 0; ks < 8; ++ks)
            wreg[g][ks] = *(const bfrag*)(wrow + ks * 32 + kg * 8);
    }

    for (int tile = blockIdx.x; tile < ntiles; tile += gridDim.x) {
        int node0 = tile * 32;
        float c[2][4] = {};
        if (tid < 96) sc_s[tid] = 0.f;
        __syncthreads();

        #pragma unroll
        for (int i = 0; i < 3; ++i) {
            const unsigned short* Xt = (i == 0) ? Xs0 : ((i == 1) ? X1 : Xs2);
            const unsigned short* h_rd = h_lds[(i + 1) & 1];
            unsigned short* h_wr = h_lds[i & 1];

            ffrag acc[2][4];
            #pragma unroll
            for (int nt = 0; nt < 2; ++nt)
                #pragma unroll
                for (int g = 0; g < 4; ++g) acc[nt][g] = (ffrag){0.f, 0.f, 0.f, 0.f};

            #pragma unroll
            for (int ks = 0; ks < 4; ++ks) {
                int kk = ks * 32 + kg * 8;
                bfrag a0 = *(const bfrag*)(Xt + (size_t)(node0 + col) * 128 + kk);
                bfrag a1 = *(const bfrag*)(Xt + (size_t)(node0 + 16 + col) * 128 + kk);
                #pragma unroll
                for (int g = 0; g < 4; ++g) {
                    acc[0][g] = __builtin_amdgcn_mfma_f32_16x16x32_bf16(a0, wreg[g][ks], acc[0][g], 0, 0, 0);
                    acc[1][g] = __builtin_amdgcn_mfma_f32_16x16x32_bf16(a1, wreg[g][ks], acc[1][g], 0, 0, 0);
                }
            }

            if (i > 0) {
                #pragma unroll
                for (int ks = 4; ks < 8; ++ks) {
                    int kh = (ks - 4) * 32 + kg * 8;
                    bfrag ah0 = *(const bfrag*)&h_rd[hoff(col, kh)];
                    bfrag ah1 = *(const bfrag*)&h_rd[hoff(16 + col, kh)];
                    #pragma unroll
                    for (int g = 0; g < 4; ++g) {
                        acc[0][g] = __builtin_amdgcn_mfma_f32_16x16x32_bf16(ah0, wreg[g][ks], acc[0][g], 0, 0, 0);
                        acc[1][g] = __builtin_amdgcn_mfma_f32_16x16x32_bf16(ah1, wreg[g][ks], acc[1][g], 0, 0, 0);
                    }
                }
            }

            #pragma unroll
            for (int nt = 0; nt < 2; ++nt) {
                #pragma unroll
                for (int r = 0; r < 4; ++r) {
                    float gi = acc[nt][0][r] + bi;
                    float gf = acc[nt][1][r] + bf_;
                    float gg = acc[nt][2][r] + bg;
                    float go = acc[nt][3][r] + bo;
                    float si = sigf(gi);
                    float sf = sigf(gf);
                    float so = sigf(go);
                    float tg = tanhfast(gg);
                    float cn = sf * c[nt][r] + si * tg;
                    float hn = so * tanhfast(cn);
                    c[nt][r] = cn;
                    int nl = nt * 16 + kg * 4 + r;
                    h_wr[hoff(nl, kch)] = f2bf(hn);
                    float v = hn * wk;
                    #pragma unroll
                    for (int mk = 1; mk < 16; mk <<= 1) v += __shfl_xor(v, mk);
                    if (col == 0) atomicAdd(&sc_s[i * 32 + nl], v);
                }
            }
            __syncthreads();
        }

        if (tid < 96) {
            int ii = tid >> 5, nl = tid & 31;
            int t = (ii == 0) ? t0 : ((ii == 1) ? 1 : (2 - t0));
            int n = node0 + nl;
            if (n < Nn) scD[(size_t)t * Nn + n] = sc_s[tid];
        }
        __syncthreads();
    }
}

// ---------------------------------------------------------------- fused head (r18-proven)
__global__ __launch_bounds__(256)
void head_k(const float* __restrict__ scA, const float* __restrict__ scB,
            const float* __restrict__ jkbias,
            const unsigned short* __restrict__ x0, const unsigned short* __restrict__ x1,
            const unsigned short* __restrict__ x2, const unsigned short* __restrict__ xb,
            const unsigned short* __restrict__ wb,
            const float* __restrict__ l1b, const float* __restrict__ l2b,
            const float* __restrict__ ow, const float* __restrict__ ob,
            float* __restrict__ out, int Nn)
{
    __shared__ unsigned short jk_lds[64][136];  // 272B rows: 16B-aligned, 2-way banks
    __shared__ unsigned short h1_lds[64][72];   // 144B rows
    __shared__ float h2_lds[64][68];
    __shared__ float al_lds[64][4];
    __shared__ float ow_lds[384];
    __shared__ float ob_lds[8];

    int tid = threadIdx.x;
    int node0 = blockIdx.x * 64;
    int wv = tid >> 6, lane = tid & 63;
    int col = lane & 15, kg = lane >> 4;

    for (int i = tid; i < 384; i += 256) ow_lds[i] = ow[i];
    if (tid < 6) ob_lds[tid] = ob[tid];

    // JK alphas (one thread per node)
    if (tid < 64) {
        int n = node0 + tid;
        float b = jkbias[0];
        float s0 = 0.f, s1 = 0.f, s2 = 0.f;
        if (n < Nn) {
            s0 = b + scA[n] + scB[n];
            s1 = b + scA[Nn + n] + scB[Nn + n];
            s2 = b + scA[2 * Nn + n] + scB[2 * Nn + n];
        }
        float mx = fmaxf(s0, fmaxf(s1, s2));
        float e0 = __expf(s0 - mx), e1 = __expf(s1 - mx), e2 = __expf(s2 - mx);
        float inv = 1.f / (e0 + e1 + e2);
        al_lds[tid][0] = e0 * inv; al_lds[tid][1] = e1 * inv; al_lds[tid][2] = e2 * inv;
    }
    __syncthreads();

    // jk tile into LDS: thread -> node tid>>2, 32 channels at (tid&3)*32
    {
        int nl = tid >> 2;
        int c0 = (tid & 3) * 32;
        float a0 = al_lds[nl][0], a1 = al_lds[nl][1], a2 = al_lds[nl][2];
        size_t base = (size_t)(node0 + nl) * 128 + c0;   // xsb buffers are Np-padded: safe
        #pragma unroll
        for (int ch = 0; ch < 4; ++ch) {
            bfrag u0 = *(const bfrag*)(x0 + base + ch * 8);
            bfrag u1 = *(const bfrag*)(x1 + base + ch * 8);
            bfrag u2 = *(const bfrag*)(x2 + base + ch * 8);
            #pragma unroll
            for (int j = 0; j < 8; ++j) {
                float v = a0 * bf2f((unsigned short)u0[j]) + a1 * bf2f((unsigned short)u1[j])
                        + a2 * bf2f((unsigned short)u2[j]);
                jk_lds[nl][c0 + ch * 8 + j] = f2bf(v);
            }
        }
    }
    __syncthreads();

    // h1 = relu(jk @ l1w^T), K=128, 64 out ch
    {
        const unsigned short* l1w = wb + 49152;
        ffrag acc[4];
        #pragma unroll
        for (int t = 0; t < 4; ++t) acc[t] = (ffrag){0.f, 0.f, 0.f, 0.f};
        #pragma unroll
        for (int ks = 0; ks < 4; ++ks) {
            int kk = ks * 32 + kg * 8;
            bfrag a = *(const bfrag*)&jk_lds[wv * 16 + col][kk];
            #pragma unroll
            for (int t = 0; t < 4; ++t) {
                bfrag b = *(const bfrag*)(l1w + (size_t)(t * 16 + col) * 128 + kk);
                acc[t] = __builtin_amdgcn_mfma_f32_16x16x32_bf16(a, b, acc[t], 0, 0, 0);
            }
        }
        #pragma unroll
        for (int t = 0; t < 4; ++t) {
            float bb = l1b[t * 16 + col];
            #pragma unroll
            for (int r = 0; r < 4; ++r) {
                float v = fmaxf(acc[t][r] + bb, 0.f);
                h1_lds[wv * 16 + kg * 4 + r][t * 16 + col] = f2bf(v);
            }
        }
    }
    __syncthreads();

    // h2 = relu([h1 | x] @ l2w^T), K=192 (64 LDS + 128 global xb)
    {
        const unsigned short* l2w = wb + 57344;
        ffrag acc[4];
        #pragma unroll
        for (int t = 0; t < 4; ++t) acc[t] = (ffrag){0.f, 0.f, 0.f, 0.f};
        #pragma unroll
        for (int ks = 0; ks < 6; ++ks) {
            int kk = ks * 32 + kg * 8;
            bfrag a;
            if (kk < 64) a = *(const bfrag*)&h1_lds[wv * 16 + col][kk];
            else         a = *(const bfrag*)(xb + (size_t)(node0 + wv * 16 + col) * 128 + (kk - 64));
            #pragma unroll
            for (int t = 0; t < 4; ++t) {
                bfrag b = *(const bfrag*)(l2w + (size_t)(t * 16 + col) * 192 + kk);
                acc[t] = __builtin_amdgcn_mfma_f32_16x16x32_bf16(a, b, acc[t], 0, 0, 0);
            }
        }
        #pragma unroll
        for (int t = 0; t < 4; ++t) {
            float bb = l2b[t * 16 + col];
            #pragma unroll
            for (int r = 0; r < 4; ++r)
                h2_lds[wv * 16 + kg * 4 + r][t * 16 + col] = fmaxf(acc[t][r] + bb, 0.f);
        }
    }
    __syncthreads();

    // logits + log_softmax (one lane per node)
    if (tid < 64) {
        int n = node0 + tid;
        if (n < Nn) {
            float l[6];
            #pragma unroll
            for (int j = 0; j < 6; ++j) l[j] = ob_lds[j];
            for (int cch = 0; cch < 64; ++cch) {
                float h = h2_lds[tid][cch];
                #pragma unroll
                for (int j = 0; j < 6; ++j) l[j] = fmaf(h, ow_lds[j * 64 + cch], l[j]);
            }
            float mx = l[0];
            #pragma unroll
            for (int j = 1; j < 6; ++j) mx = fmaxf(mx, l[j]);
            float se = 0.f;
            #pragma unroll
            for (int j = 0; j < 6; ++j) se += __expf(l[j] - mx);
            float ls = logf(se) + mx;
            #pragma unroll
            for (int j = 0; j < 6; ++j) out[(size_t)n * 6 + j] = l[j] - ls;
        }
    }
}

// ---------------------------------------------------------------- launch
extern "C" void kernel_launch(void* const* d_in, const int* in_sizes, int n_in,
                              void* d_out, int out_size, void* d_ws, size_t ws_size,
                              hipStream_t stream) {
    const float* x   = (const float*)d_in[0];
    const int*   ei  = (const int*)d_in[1];
    const float* W1  = (const float*)d_in[2];
    const float* a1s = (const float*)d_in[3];
    const float* a1d = (const float*)d_in[4];
    const float* b1  = (const float*)d_in[5];
    const float* Ws  = (const float*)d_in[6];
    const float* ass = (const float*)d_in[7];
    const float* asd = (const float*)d_in[8];
    const float* bs  = (const float*)d_in[9];
    const float* Wih = (const float*)d_in[10];
    const float* Whh = (const float*)d_in[11];
    const float* bih = (const float*)d_in[12];
    const float* bhh = (const float*)d_in[13];
    const float* jkw = (const float*)d_in[14];
    const float* jkb_b = (const float*)d_in[15];
    const float* l1w = (const float*)d_in[16];
    const float* l1b = (const float*)d_in[17];
    const float* l2w = (const float*)d_in[18];
    const float* l2b = (const float*)d_in[19];
    const float* ow  = (const float*)d_in[20];
    const float* ob  = (const float*)d_in[21];
    float* out = (float*)d_out;

    int Nn = in_sizes[0] / 128;
    int E  = in_sizes[1] / 2;
    int ET = E + Nn;
    size_t Np = ((size_t)Nn + 63) & ~(size_t)63;
    size_t Fp = Np * 128;

    float* w = (float*)d_ws;
    float* es    = w;                    // [2Nn]
    float* ed    = es + 2*Nn;            // [2Nn]
    float* score = ed + 2*Nn;            // [6Nn] (two per-dir [3Nn] buffers)
    float* bsum  = score + 6*Nn;         // [1024]
    float* h2    = bsum + 1024;          // [Nn*64] (unused, layout keep)
    unsigned short* xb   = (unsigned short*)(h2 + (size_t)Nn*64);  // [Fp]
    unsigned short* xpb  = xb + Fp;      // [Fp]
    unsigned short* xsb0 = xpb + Fp;
    unsigned short* xsb1 = xsb0 + Fp;
    unsigned short* xsb2 = xsb1 + Fp;
    unsigned short* h1b  = xsb2 + Fp;    // [Fp] (unused)
    unsigned short* Wp   = h1b + Fp;     // [2*512*256]
    unsigned short* wb   = Wp + 2*512*256; // [69632]
    int* deg     = (int*)(wb + 69632);
    int* row_ptr = deg + Nn;
    int* cursor  = row_ptr + Nn;
    int* part    = cursor + Nn;          // [64]
    int* csr_src = part + 64;            // [ET]

    // ---- CSR + prep (edges identical for all 3 layers)
    int nb1 = CDIV(Nn, 1024);
    int nprep = 262144 + 69632 + Nn * 128;
    int nhp = nprep > ET ? nprep : ET;
    hipMemsetAsync(deg, 0, (size_t)Nn * 4, stream);
    hist_prep_k<<<CDIV(nhp, 256), 256, 0, stream>>>(ei, E, ET, deg,
                                                    Wih, Whh, bih, bhh, Wp, bsum,
                                                    W1, Ws, l1w, l2w, wb, x, xb, Nn * 128);
    scan1_k<<<nb1, 256, 0, stream>>>(deg, row_ptr, part, Nn);
    scan23_k<<<CDIV(Nn, 256), 256, 0, stream>>>(part, nb1, row_ptr, cursor, Nn);
    fill_k<<<CDIV(ET, 256), 256, 0, stream>>>(ei, E, ET, cursor, csr_src);

    unsigned short* xsb_arr[3] = {xsb0, xsb1, xsb2};
    int gblk = CDIV(Nn, 64);

    for (int l = 0; l < 3; ++l) {
        const float* asl = (l == 0) ? a1s : ass + (size_t)(l-1) * 128;
        const float* adl = (l == 0) ? a1d : asd + (size_t)(l-1) * 128;
        const float* bl  = (l == 0) ? b1  : bs  + (size_t)(l-1) * 128;
        const unsigned short* Ain = (l == 0) ? xb : xsb_arr[l-1];
        const unsigned short* Wbl = wb + (size_t)l * 16384;
        gemm_mfma_k<8,128,128,false,true,true><<<gblk, 256, 0, stream>>>(
            Ain, Ain, 128, Wbl, nullptr, xpb, nullptr, asl, adl, es, ed, Nn);
        gat_agg_k<<<CDIV(Nn, 16), 256, 0, stream>>>(csr_src, row_ptr, deg, xpb, es, ed, bl,
                                                    xsb_arr[l], Nn, l > 0);
    }

    int ntiles = CDIV(Nn, 32);
    int gx = ntiles < 128 ? ntiles : 128;
    lstm_all_k<<<dim3(gx, 2), 512, 0, stream>>>(xsb0, xsb1, xsb2, Wp, bsum, jkw, score, Nn, ntiles);

    head_k<<<gblk, 256, 0, stream>>>(score, score + (size_t)3*Nn, jkb_b,
                                     xsb0, xsb1, xsb2, xb, wb, l1b, l2b, ow, ob, out, Nn);
}